// Round 1
// baseline (748.100 us; speedup 1.0000x reference)
//
#include <hip/hip_runtime.h>
#include <math.h>

#define NEG_SLOPE 0.2f

// ---------------- CSR construction ----------------

__global__ void fill_zero_i32(int* __restrict__ p, int n) {
    int i = blockIdx.x * blockDim.x + threadIdx.x;
    if (i < n) p[i] = 0;
}

__global__ void hist_kernel(const int* __restrict__ dst, int E, int N, int* __restrict__ cnt) {
    int i = blockIdx.x * blockDim.x + threadIdx.x;
    int tot = E + N;
    if (i < tot) {
        int d = (i < E) ? dst[i] : (i - E);   // self-loops appended
        atomicAdd(&cnt[d], 1);
    }
}

__global__ __launch_bounds__(1024) void scan_kernel(const int* __restrict__ cnt,
                                                    int* __restrict__ rowptr,
                                                    int* __restrict__ cursor, int N) {
    __shared__ int wsums[16];
    __shared__ int s_base;
    int tid = threadIdx.x, lane = tid & 63, w = tid >> 6;
    if (tid == 0) s_base = 0;
    __syncthreads();
    for (int c0 = 0; c0 < N; c0 += 1024) {
        int idx = c0 + tid;
        int v = (idx < N) ? cnt[idx] : 0;
        int incl = v;
        #pragma unroll
        for (int off = 1; off < 64; off <<= 1) {
            int t = __shfl_up(incl, off, 64);
            if (lane >= off) incl += t;
        }
        if (lane == 63) wsums[w] = incl;
        __syncthreads();
        int base = s_base;
        int wbase = 0;
        #pragma unroll
        for (int j = 0; j < 16; j++) { if (j < w) wbase += wsums[j]; }
        int excl = base + wbase + incl - v;
        if (idx < N) { rowptr[idx] = excl; cursor[idx] = excl; }
        __syncthreads();
        if (tid == 1023) s_base = base + wbase + incl;
        __syncthreads();
    }
    if (tid == 0) rowptr[N] = s_base;
}

__global__ void scatter_kernel(const int* __restrict__ src, const int* __restrict__ dst,
                               int E, int N, int* __restrict__ cursor, int* __restrict__ col) {
    int i = blockIdx.x * blockDim.x + threadIdx.x;
    int tot = E + N;
    if (i < tot) {
        int s = (i < E) ? src[i] : (i - E);
        int d = (i < E) ? dst[i] : (i - E);
        int pos = atomicAdd(&cursor[d], 1);
        col[pos] = s;
    }
}

// ---------------- Layer 1 GEMM: h1 = x @ W1, plus alpha_src/alpha_dst ----------------
// block: 512 threads, 128 rows/block; thread (r = tid&127, g = tid>>7) computes head g (32 cols).

__global__ __launch_bounds__(512) void gemm1_kernel(const float* __restrict__ x,
                                                    const float* __restrict__ W,
                                                    const float* __restrict__ a_s,
                                                    const float* __restrict__ a_d,
                                                    float* __restrict__ h1,
                                                    float* __restrict__ as1,
                                                    float* __restrict__ ad1, int N) {
    __shared__ float Ws[128 * 128];     // 64 KB
    __shared__ float xs[128 * 129];     // 66 KB (pad 129 -> (r+k)%32 banks, 2-way = free)
    int tid = threadIdx.x;
    {
        const float4* W4 = (const float4*)W;
        float4* Ws4 = (float4*)Ws;
        for (int i = tid; i < 4096; i += 512) Ws4[i] = W4[i];
    }
    int row0 = blockIdx.x * 128;
    for (int i = tid; i < 128 * 128; i += 512) {
        int r = i >> 7, k = i & 127;
        int row = row0 + r;
        xs[r * 129 + k] = (row < N) ? x[row * 128 + k] : 0.f;
    }
    __syncthreads();

    int r = tid & 127, g = tid >> 7;
    float acc[32];
    #pragma unroll
    for (int j = 0; j < 32; j++) acc[j] = 0.f;

    for (int k = 0; k < 128; k++) {
        float xv = xs[r * 129 + k];
        const float* w = &Ws[k * 128 + g * 32];   // wave-uniform address -> LDS broadcast
        #pragma unroll
        for (int j = 0; j < 32; j++) acc[j] = fmaf(xv, w[j], acc[j]);
    }

    int row = row0 + r;
    if (row < N) {
        float sd = 0.f, dd = 0.f;
        #pragma unroll
        for (int j = 0; j < 32; j++) {
            sd = fmaf(acc[j], a_s[g * 32 + j], sd);
            dd = fmaf(acc[j], a_d[g * 32 + j], dd);
        }
        as1[row * 4 + g] = sd;
        ad1[row * 4 + g] = dd;
        float4* o = (float4*)&h1[row * 128 + g * 32];
        #pragma unroll
        for (int j4 = 0; j4 < 8; j4++)
            o[j4] = make_float4(acc[j4 * 4], acc[j4 * 4 + 1], acc[j4 * 4 + 2], acc[j4 * 4 + 3]);
    }
}

// ---------------- Layer 1 aggregation: one wave per dst node ----------------
// out[n] = relu( (sum_e exp(lrelu(as[s]+ad[n])) * h1[s]) / sum_e exp(...) + b1 )
// softmax max-subtraction omitted: exactly invariant in real arithmetic, |e| <= ~5 here.

__global__ __launch_bounds__(256) void agg1_kernel(const int* __restrict__ rowptr,
                                                   const int* __restrict__ col,
                                                   const float* __restrict__ h1,
                                                   const float* __restrict__ as1,
                                                   const float* __restrict__ ad1,
                                                   const float* __restrict__ b1,
                                                   float* __restrict__ out1, int N) {
    int lane = threadIdx.x & 63;
    int n = blockIdx.x * 4 + (threadIdx.x >> 6);
    if (n >= N) return;
    int h_lo = lane >> 5;                      // head of channel `lane` (0 or 1)
    float ad_lo = ad1[n * 4 + h_lo];
    float ad_hi = ad1[n * 4 + h_lo + 2];       // head of channel lane+64 (2 or 3)
    int beg = rowptr[n], end = rowptr[n + 1];
    float acc_lo = 0.f, acc_hi = 0.f, den_lo = 0.f, den_hi = 0.f;
    for (int i = beg; i < end; i++) {
        int s = col[i];
        float e_lo = as1[s * 4 + h_lo] + ad_lo;
        float e_hi = as1[s * 4 + h_lo + 2] + ad_hi;
        e_lo = (e_lo > 0.f) ? e_lo : NEG_SLOPE * e_lo;
        e_hi = (e_hi > 0.f) ? e_hi : NEG_SLOPE * e_hi;
        float ex_lo = __expf(e_lo);
        float ex_hi = __expf(e_hi);
        den_lo += ex_lo;
        den_hi += ex_hi;
        acc_lo = fmaf(ex_lo, h1[s * 128 + lane], acc_lo);
        acc_hi = fmaf(ex_hi, h1[s * 128 + 64 + lane], acc_hi);
    }
    float v_lo = acc_lo / den_lo + b1[lane];
    float v_hi = acc_hi / den_hi + b1[lane + 64];
    out1[n * 128 + lane] = v_lo > 0.f ? v_lo : 0.f;     // fused ReLU (layer-2 input)
    out1[n * 128 + 64 + lane] = v_hi > 0.f ? v_hi : 0.f;
}

// ---------------- Layer 2 GEMM: h2 = relu_h @ W2, plus as2/ad2 ----------------
// block: 256 threads, 64 rows; thread (r=tid&63, g=tid>>6) computes 8 cols.

__global__ __launch_bounds__(256) void gemm2_kernel(const float* __restrict__ xin,
                                                    const float* __restrict__ W,
                                                    const float* __restrict__ a_s,
                                                    const float* __restrict__ a_d,
                                                    float* __restrict__ h2,
                                                    float* __restrict__ as2,
                                                    float* __restrict__ ad2, int N) {
    __shared__ float Ws[128 * 32];     // 16 KB
    __shared__ float xs[64 * 129];     // 33 KB
    __shared__ float red[64 * 8];
    int tid = threadIdx.x;
    {
        const float4* W4 = (const float4*)W;
        float4* Ws4 = (float4*)Ws;
        for (int i = tid; i < 1024; i += 256) Ws4[i] = W4[i];
    }
    int row0 = blockIdx.x * 64;
    for (int i = tid; i < 64 * 128; i += 256) {
        int r = i >> 7, k = i & 127;
        int row = row0 + r;
        xs[r * 129 + k] = (row < N) ? xin[row * 128 + k] : 0.f;
    }
    __syncthreads();

    int r = tid & 63, g = tid >> 6;
    float acc[8];
    #pragma unroll
    for (int j = 0; j < 8; j++) acc[j] = 0.f;
    for (int k = 0; k < 128; k++) {
        float xv = xs[r * 129 + k];
        const float* w = &Ws[k * 32 + g * 8];
        #pragma unroll
        for (int j = 0; j < 8; j++) acc[j] = fmaf(xv, w[j], acc[j]);
    }

    float sd = 0.f, dd = 0.f;
    #pragma unroll
    for (int j = 0; j < 8; j++) {
        sd = fmaf(acc[j], a_s[g * 8 + j], sd);
        dd = fmaf(acc[j], a_d[g * 8 + j], dd);
    }
    red[r * 8 + g] = sd;
    red[r * 8 + 4 + g] = dd;
    int row = row0 + r;
    if (row < N) {
        float4* o = (float4*)&h2[row * 32 + g * 8];
        o[0] = make_float4(acc[0], acc[1], acc[2], acc[3]);
        o[1] = make_float4(acc[4], acc[5], acc[6], acc[7]);
    }
    __syncthreads();
    if (tid < 64 && row0 + tid < N) {
        as2[row0 + tid] = red[tid * 8 + 0] + red[tid * 8 + 1] + red[tid * 8 + 2] + red[tid * 8 + 3];
        ad2[row0 + tid] = red[tid * 8 + 4] + red[tid * 8 + 5] + red[tid * 8 + 6] + red[tid * 8 + 7];
    }
}

// ---------------- Layer 2 aggregation: half-wave (32 lanes) per dst node ----------------

__global__ __launch_bounds__(256) void agg2_kernel(const int* __restrict__ rowptr,
                                                   const int* __restrict__ col,
                                                   const float* __restrict__ h2,
                                                   const float* __restrict__ as2,
                                                   const float* __restrict__ ad2,
                                                   const float* __restrict__ b2,
                                                   float* __restrict__ out, int N) {
    int lane = threadIdx.x & 63;
    int sub = lane >> 5, c = lane & 31;
    int n = (blockIdx.x * 4 + (threadIdx.x >> 6)) * 2 + sub;
    if (n >= N) return;
    float adn = ad2[n];
    float acc = 0.f, den = 0.f;
    int beg = rowptr[n], end = rowptr[n + 1];
    for (int i = beg; i < end; i++) {
        int s = col[i];
        float e = as2[s] + adn;
        e = (e > 0.f) ? e : NEG_SLOPE * e;
        float ex = __expf(e);
        den += ex;
        acc = fmaf(ex, h2[s * 32 + c], acc);
    }
    out[n * 32 + c] = acc / den + b2[c];
}

// ---------------- launch ----------------

extern "C" void kernel_launch(void* const* d_in, const int* in_sizes, int n_in,
                              void* d_out, int out_size, void* d_ws, size_t ws_size,
                              hipStream_t stream) {
    const float* x    = (const float*)d_in[0];
    const int*   ei   = (const int*)d_in[1];
    const float* W1   = (const float*)d_in[2];
    const float* a_s1 = (const float*)d_in[3];
    const float* a_d1 = (const float*)d_in[4];
    const float* b1   = (const float*)d_in[5];
    const float* W2   = (const float*)d_in[6];
    const float* a_s2 = (const float*)d_in[7];
    const float* a_d2 = (const float*)d_in[8];
    const float* b2   = (const float*)d_in[9];

    int N = in_sizes[0] / 128;
    int E = in_sizes[1] / 2;
    const int* srcA = ei;
    const int* dstA = ei + E;

    char* ws = (char*)d_ws;
    size_t off = 0;
    auto alloc = [&](size_t bytes) {
        void* p = ws + off;
        off += (bytes + 255) & ~(size_t)255;
        return p;
    };
    float* h1     = (float*)alloc((size_t)N * 128 * 4);
    float* out1   = (float*)alloc((size_t)N * 128 * 4);
    float* h2     = (float*)alloc((size_t)N * 32 * 4);
    float* as1    = (float*)alloc((size_t)N * 4 * 4);
    float* ad1    = (float*)alloc((size_t)N * 4 * 4);
    float* as2    = (float*)alloc((size_t)N * 4);
    float* ad2    = (float*)alloc((size_t)N * 4);
    int*   rowptr = (int*)alloc((size_t)(N + 1) * 4);
    int*   cnt    = (int*)alloc((size_t)N * 4);
    int*   cursor = (int*)alloc((size_t)N * 4);
    int*   col    = (int*)alloc((size_t)(E + N) * 4);

    int Etot = E + N;

    hipLaunchKernelGGL(fill_zero_i32, dim3((N + 255) / 256), dim3(256), 0, stream, cnt, N);
    hipLaunchKernelGGL(hist_kernel, dim3((Etot + 255) / 256), dim3(256), 0, stream, dstA, E, N, cnt);
    hipLaunchKernelGGL(scan_kernel, dim3(1), dim3(1024), 0, stream, cnt, rowptr, cursor, N);
    hipLaunchKernelGGL(scatter_kernel, dim3((Etot + 255) / 256), dim3(256), 0, stream,
                       srcA, dstA, E, N, cursor, col);
    hipLaunchKernelGGL(gemm1_kernel, dim3((N + 127) / 128), dim3(512), 0, stream,
                       x, W1, a_s1, a_d1, h1, as1, ad1, N);
    hipLaunchKernelGGL(agg1_kernel, dim3((N + 3) / 4), dim3(256), 0, stream,
                       rowptr, col, h1, as1, ad1, b1, out1, N);
    hipLaunchKernelGGL(gemm2_kernel, dim3((N + 63) / 64), dim3(256), 0, stream,
                       out1, W2, a_s2, a_d2, h2, as2, ad2, N);
    hipLaunchKernelGGL(agg2_kernel, dim3((N + 7) / 8), dim3(256), 0, stream,
                       rowptr, col, h2, as2, ad2, b2, (float*)d_out, N);
}

// Round 2
// 481.181 us; speedup vs baseline: 1.5547x; 1.5547x over previous
//
#include <hip/hip_runtime.h>
#include <math.h>

#define NEG_SLOPE 0.2f

// ---------------- CSR construction ----------------

__global__ void fill_zero_i32(int* __restrict__ p, int n) {
    int i = blockIdx.x * blockDim.x + threadIdx.x;
    if (i < n) p[i] = 0;
}

__global__ void hist_kernel(const int* __restrict__ dst, int E, int N, int* __restrict__ cnt) {
    int i = blockIdx.x * blockDim.x + threadIdx.x;
    int tot = E + N;
    if (i < tot) {
        int d = (i < E) ? dst[i] : (i - E);   // self-loops appended
        atomicAdd(&cnt[d], 1);
    }
}

// 3-phase scan: block sums -> scan partials -> per-block exclusive scan
__global__ __launch_bounds__(256) void block_sum_kernel(const int* __restrict__ cnt,
                                                        int* __restrict__ psum, int N) {
    __shared__ int red[4];
    int tid = threadIdx.x;
    int idx = blockIdx.x * 256 + tid;
    int v = (idx < N) ? cnt[idx] : 0;
    #pragma unroll
    for (int off = 1; off < 64; off <<= 1) v += __shfl_xor(v, off, 64);
    if ((tid & 63) == 0) red[tid >> 6] = v;
    __syncthreads();
    if (tid == 0) psum[blockIdx.x] = red[0] + red[1] + red[2] + red[3];
}

__global__ __launch_bounds__(1024) void scan_psum_kernel(int* __restrict__ psum,
                                                         int* __restrict__ rowptr,
                                                         int nb, int N) {
    __shared__ int ws[16];
    int tid = threadIdx.x, lane = tid & 63, w = tid >> 6;
    int v = (tid < nb) ? psum[tid] : 0;
    int incl = v;
    #pragma unroll
    for (int off = 1; off < 64; off <<= 1) {
        int t = __shfl_up(incl, off, 64);
        if (lane >= off) incl += t;
    }
    if (lane == 63) ws[w] = incl;
    __syncthreads();
    int wbase = 0;
    #pragma unroll
    for (int j = 0; j < 16; j++) { if (j < w) wbase += ws[j]; }
    if (tid < nb) psum[tid] = wbase + incl - v;   // exclusive
    if (tid == 1023) rowptr[N] = wbase + incl;    // total (zeros beyond nb)
}

__global__ __launch_bounds__(256) void scan_final_kernel(const int* __restrict__ cnt,
                                                         const int* __restrict__ psum,
                                                         int* __restrict__ rowptr,
                                                         int* __restrict__ cursor, int N) {
    __shared__ int ws[4];
    int tid = threadIdx.x, lane = tid & 63, w = tid >> 6;
    int idx = blockIdx.x * 256 + tid;
    int v = (idx < N) ? cnt[idx] : 0;
    int incl = v;
    #pragma unroll
    for (int off = 1; off < 64; off <<= 1) {
        int t = __shfl_up(incl, off, 64);
        if (lane >= off) incl += t;
    }
    if (lane == 63) ws[w] = incl;
    __syncthreads();
    int wbase = 0;
    #pragma unroll
    for (int j = 0; j < 4; j++) { if (j < w) wbase += ws[j]; }
    int excl = psum[blockIdx.x] + wbase + incl - v;
    if (idx < N) { rowptr[idx] = excl; cursor[idx] = excl; }
}

__global__ void scatter_kernel(const int* __restrict__ src, const int* __restrict__ dst,
                               int E, int N, int* __restrict__ cursor, int* __restrict__ col) {
    int i = blockIdx.x * blockDim.x + threadIdx.x;
    int tot = E + N;
    if (i < tot) {
        int s = (i < E) ? src[i] : (i - E);
        int d = (i < E) ? dst[i] : (i - E);
        int pos = atomicAdd(&cursor[d], 1);
        col[pos] = s;
    }
}

// ---------------- Layer 1 GEMM: h1 = x @ W1 (register-tiled), plus as1/ad1 ----------------
// 128 rows x 128 cols per block, 512 threads; thread (cc=tid&15, rr=tid>>4) owns
// rows rr*4..+3, cols cc*8..+7 (4x8 = 32 acc). K chunked by 4: 1 ds_read_b128 of x
// per 4 k-steps per row.

#define XPAD 132

__global__ __launch_bounds__(512) void gemm1_kernel(const float* __restrict__ x,
                                                    const float* __restrict__ W,
                                                    const float* __restrict__ a_s,
                                                    const float* __restrict__ a_d,
                                                    float* __restrict__ h1,
                                                    float* __restrict__ as1,
                                                    float* __restrict__ ad1, int N) {
    __shared__ float xs[128 * XPAD];       // 67.6 KB row-major [r][k], pad 132
    __shared__ float Ws[128 * 128];        // 64 KB [k][c]
    __shared__ float red[2 * 128 * 16];    // 16 KB (s/d partials)
    int tid = threadIdx.x;
    int row0 = blockIdx.x * 128;
    {
        const float4* W4 = (const float4*)W;
        float4* Ws4 = (float4*)Ws;
        #pragma unroll
        for (int it = 0; it < 8; it++) Ws4[tid + it * 512] = W4[tid + it * 512];
    }
    #pragma unroll
    for (int it = 0; it < 8; it++) {
        int i = tid + it * 512;            // 0..4095
        int r = i >> 5, k4 = i & 31;
        int row = row0 + r;
        float4 v = (row < N) ? ((const float4*)x)[row * 32 + k4] : make_float4(0.f, 0.f, 0.f, 0.f);
        *(float4*)&xs[r * XPAD + k4 * 4] = v;
    }
    __syncthreads();

    int cc = tid & 15, rr = tid >> 4;
    float acc[4][8];
    #pragma unroll
    for (int r = 0; r < 4; r++)
        #pragma unroll
        for (int j = 0; j < 8; j++) acc[r][j] = 0.f;

    for (int k4 = 0; k4 < 32; k4++) {
        float4 xk[4];
        #pragma unroll
        for (int r = 0; r < 4; r++)
            xk[r] = *(const float4*)&xs[(rr * 4 + r) * XPAD + k4 * 4];
        #pragma unroll
        for (int kk = 0; kk < 4; kk++) {
            int k = k4 * 4 + kk;
            float4 w0 = *(const float4*)&Ws[k * 128 + cc * 8];
            float4 w1 = *(const float4*)&Ws[k * 128 + cc * 8 + 4];
            #pragma unroll
            for (int r = 0; r < 4; r++) {
                float xv = ((const float*)&xk[r])[kk];
                acc[r][0] = fmaf(xv, w0.x, acc[r][0]);
                acc[r][1] = fmaf(xv, w0.y, acc[r][1]);
                acc[r][2] = fmaf(xv, w0.z, acc[r][2]);
                acc[r][3] = fmaf(xv, w0.w, acc[r][3]);
                acc[r][4] = fmaf(xv, w1.x, acc[r][4]);
                acc[r][5] = fmaf(xv, w1.y, acc[r][5]);
                acc[r][6] = fmaf(xv, w1.z, acc[r][6]);
                acc[r][7] = fmaf(xv, w1.w, acc[r][7]);
            }
        }
    }

    // attention-coefficient partials: thread's 8 cols are all in head cc>>2
    #pragma unroll
    for (int r = 0; r < 4; r++) {
        float sd = 0.f, dd = 0.f;
        #pragma unroll
        for (int j = 0; j < 8; j++) {
            sd = fmaf(acc[r][j], a_s[cc * 8 + j], sd);
            dd = fmaf(acc[r][j], a_d[cc * 8 + j], dd);
        }
        red[(rr * 4 + r) * 16 + cc] = sd;
        red[2048 + (rr * 4 + r) * 16 + cc] = dd;
    }
    // store h1
    #pragma unroll
    for (int r = 0; r < 4; r++) {
        int row = row0 + rr * 4 + r;
        if (row < N) {
            *(float4*)&h1[row * 128 + cc * 8]     = make_float4(acc[r][0], acc[r][1], acc[r][2], acc[r][3]);
            *(float4*)&h1[row * 128 + cc * 8 + 4] = make_float4(acc[r][4], acc[r][5], acc[r][6], acc[r][7]);
        }
    }
    __syncthreads();
    {
        int row = tid >> 2, h = tid & 3;
        if (row0 + row < N) {
            float s = red[row * 16 + h * 4] + red[row * 16 + h * 4 + 1] +
                      red[row * 16 + h * 4 + 2] + red[row * 16 + h * 4 + 3];
            float d = red[2048 + row * 16 + h * 4] + red[2048 + row * 16 + h * 4 + 1] +
                      red[2048 + row * 16 + h * 4 + 2] + red[2048 + row * 16 + h * 4 + 3];
            as1[(row0 + row) * 4 + h] = s;
            ad1[(row0 + row) * 4 + h] = d;
        }
    }
}

// ---------------- Layer 1 aggregation: one wave per dst node, float2/lane, unroll x4 ----

__device__ __forceinline__ float sel4(float4 a, int h) {
    return h < 2 ? (h == 0 ? a.x : a.y) : (h == 2 ? a.z : a.w);
}

__global__ __launch_bounds__(256) void agg1_kernel(const int* __restrict__ rowptr,
                                                   const int* __restrict__ col,
                                                   const float* __restrict__ h1,
                                                   const float* __restrict__ as1,
                                                   const float* __restrict__ ad1,
                                                   const float* __restrict__ b1,
                                                   float* __restrict__ out1, int N) {
    int lane = threadIdx.x & 63;
    int wid = __builtin_amdgcn_readfirstlane(threadIdx.x >> 6);
    int n = blockIdx.x * 4 + wid;
    if (n >= N) return;
    int hh = lane >> 4;                       // head of channels 2*lane, 2*lane+1
    const float4* as4 = (const float4*)as1;
    const float2* h1v = (const float2*)h1;
    float adn = sel4(((const float4*)ad1)[n], hh);
    int beg = rowptr[n], end = rowptr[n + 1];
    float ax = 0.f, ay = 0.f, den = 0.f;
    int i = beg;
    for (; i + 4 <= end; i += 4) {
        int s0 = col[i], s1 = col[i + 1], s2 = col[i + 2], s3 = col[i + 3];
        float4 A0 = as4[s0], A1 = as4[s1], A2 = as4[s2], A3 = as4[s3];
        float2 v0 = h1v[s0 * 64 + lane];
        float2 v1 = h1v[s1 * 64 + lane];
        float2 v2 = h1v[s2 * 64 + lane];
        float2 v3 = h1v[s3 * 64 + lane];
        float e0 = sel4(A0, hh) + adn;
        float e1 = sel4(A1, hh) + adn;
        float e2 = sel4(A2, hh) + adn;
        float e3 = sel4(A3, hh) + adn;
        e0 = fmaxf(e0, e0 * NEG_SLOPE);
        e1 = fmaxf(e1, e1 * NEG_SLOPE);
        e2 = fmaxf(e2, e2 * NEG_SLOPE);
        e3 = fmaxf(e3, e3 * NEG_SLOPE);
        float ex0 = __expf(e0), ex1 = __expf(e1), ex2 = __expf(e2), ex3 = __expf(e3);
        den += ex0 + ex1 + ex2 + ex3;
        ax = fmaf(ex0, v0.x, ax); ay = fmaf(ex0, v0.y, ay);
        ax = fmaf(ex1, v1.x, ax); ay = fmaf(ex1, v1.y, ay);
        ax = fmaf(ex2, v2.x, ax); ay = fmaf(ex2, v2.y, ay);
        ax = fmaf(ex3, v3.x, ax); ay = fmaf(ex3, v3.y, ay);
    }
    for (; i < end; i++) {
        int s = col[i];
        float2 v = h1v[s * 64 + lane];
        float e = sel4(as4[s], hh) + adn;
        e = fmaxf(e, e * NEG_SLOPE);
        float ex = __expf(e);
        den += ex;
        ax = fmaf(ex, v.x, ax); ay = fmaf(ex, v.y, ay);
    }
    float2 bb = ((const float2*)b1)[lane];
    float2 o;
    o.x = fmaxf(ax / den + bb.x, 0.f);
    o.y = fmaxf(ay / den + bb.y, 0.f);
    ((float2*)out1)[n * 64 + lane] = o;
}

// ---------------- Layer 2 GEMM: h2 = relu_h @ W2, plus as2/ad2 ----------------

__global__ __launch_bounds__(256) void gemm2_kernel(const float* __restrict__ xin,
                                                    const float* __restrict__ W,
                                                    const float* __restrict__ a_s,
                                                    const float* __restrict__ a_d,
                                                    float* __restrict__ h2,
                                                    float* __restrict__ as2,
                                                    float* __restrict__ ad2, int N) {
    __shared__ float Ws[128 * 32];
    __shared__ float xs[64 * 129];
    __shared__ float red[64 * 8];
    int tid = threadIdx.x;
    {
        const float4* W4 = (const float4*)W;
        float4* Ws4 = (float4*)Ws;
        #pragma unroll
        for (int it = 0; it < 4; it++) Ws4[tid + it * 256] = W4[tid + it * 256];
    }
    int row0 = blockIdx.x * 64;
    #pragma unroll
    for (int it = 0; it < 8; it++) {
        int i = tid + it * 256;           // 0..2047 -> float4 granules
        int r = i >> 5, k4 = i & 31;
        int row = row0 + r;
        float4 v = (row < N) ? ((const float4*)xin)[row * 32 + k4] : make_float4(0.f, 0.f, 0.f, 0.f);
        *(float4*)&xs[r * 129 + k4 * 4] = v;  // 129 not /4... use scalar writes
    }
    __syncthreads();

    int r = tid & 63, g = tid >> 6;
    float acc[8];
    #pragma unroll
    for (int j = 0; j < 8; j++) acc[j] = 0.f;
    for (int k = 0; k < 128; k++) {
        float xv = xs[r * 129 + k];
        const float* w = &Ws[k * 32 + g * 8];
        #pragma unroll
        for (int j = 0; j < 8; j++) acc[j] = fmaf(xv, w[j], acc[j]);
    }

    float sd = 0.f, dd = 0.f;
    #pragma unroll
    for (int j = 0; j < 8; j++) {
        sd = fmaf(acc[j], a_s[g * 8 + j], sd);
        dd = fmaf(acc[j], a_d[g * 8 + j], dd);
    }
    red[r * 8 + g] = sd;
    red[r * 8 + 4 + g] = dd;
    int row = row0 + r;
    if (row < N) {
        float4* o = (float4*)&h2[row * 32 + g * 8];
        o[0] = make_float4(acc[0], acc[1], acc[2], acc[3]);
        o[1] = make_float4(acc[4], acc[5], acc[6], acc[7]);
    }
    __syncthreads();
    if (tid < 64 && row0 + tid < N) {
        as2[row0 + tid] = red[tid * 8 + 0] + red[tid * 8 + 1] + red[tid * 8 + 2] + red[tid * 8 + 3];
        ad2[row0 + tid] = red[tid * 8 + 4] + red[tid * 8 + 5] + red[tid * 8 + 6] + red[tid * 8 + 7];
    }
}

// ---------------- Layer 2 aggregation: one wave per node, 2 edges across halves, x4 ----

__global__ __launch_bounds__(256) void agg2_kernel(const int* __restrict__ rowptr,
                                                   const int* __restrict__ col,
                                                   const float* __restrict__ h2,
                                                   const float* __restrict__ as2,
                                                   const float* __restrict__ ad2,
                                                   const float* __restrict__ b2,
                                                   float* __restrict__ out, int N) {
    int lane = threadIdx.x & 63;
    int wid = __builtin_amdgcn_readfirstlane(threadIdx.x >> 6);
    int n = blockIdx.x * 4 + wid;
    if (n >= N) return;
    int half = lane >> 5, c = lane & 31;
    float adn = ad2[n];
    int beg = rowptr[n], end = rowptr[n + 1];
    float acc = 0.f, den = 0.f;
    int i = beg;
    for (; i + 8 <= end; i += 8) {
        int s0 = col[i + half];
        int s1 = col[i + 2 + half];
        int s2 = col[i + 4 + half];
        int s3 = col[i + 6 + half];
        float a0 = as2[s0], a1 = as2[s1], a2 = as2[s2], a3 = as2[s3];
        float v0 = h2[s0 * 32 + c], v1 = h2[s1 * 32 + c];
        float v2 = h2[s2 * 32 + c], v3 = h2[s3 * 32 + c];
        float e0 = a0 + adn, e1 = a1 + adn, e2 = a2 + adn, e3 = a3 + adn;
        e0 = fmaxf(e0, e0 * NEG_SLOPE);
        e1 = fmaxf(e1, e1 * NEG_SLOPE);
        e2 = fmaxf(e2, e2 * NEG_SLOPE);
        e3 = fmaxf(e3, e3 * NEG_SLOPE);
        float ex0 = __expf(e0), ex1 = __expf(e1), ex2 = __expf(e2), ex3 = __expf(e3);
        den += ex0 + ex1 + ex2 + ex3;
        acc = fmaf(ex0, v0, acc);
        acc = fmaf(ex1, v1, acc);
        acc = fmaf(ex2, v2, acc);
        acc = fmaf(ex3, v3, acc);
    }
    for (; i + 2 <= end; i += 2) {
        int s = col[i + half];
        float e = as2[s] + adn;
        e = fmaxf(e, e * NEG_SLOPE);
        float ex = __expf(e);
        den += ex;
        acc = fmaf(ex, h2[s * 32 + c], acc);
    }
    if (i < end && half == 0) {
        int s = col[i];
        float e = as2[s] + adn;
        e = fmaxf(e, e * NEG_SLOPE);
        float ex = __expf(e);
        den += ex;
        acc = fmaf(ex, h2[s * 32 + c], acc);
    }
    den += __shfl_xor(den, 32, 64);
    acc += __shfl_xor(acc, 32, 64);
    if (half == 0) out[n * 32 + c] = acc / den + b2[c];
}

// ---------------- launch ----------------

extern "C" void kernel_launch(void* const* d_in, const int* in_sizes, int n_in,
                              void* d_out, int out_size, void* d_ws, size_t ws_size,
                              hipStream_t stream) {
    const float* x    = (const float*)d_in[0];
    const int*   ei   = (const int*)d_in[1];
    const float* W1   = (const float*)d_in[2];
    const float* a_s1 = (const float*)d_in[3];
    const float* a_d1 = (const float*)d_in[4];
    const float* b1   = (const float*)d_in[5];
    const float* W2   = (const float*)d_in[6];
    const float* a_s2 = (const float*)d_in[7];
    const float* a_d2 = (const float*)d_in[8];
    const float* b2   = (const float*)d_in[9];

    int N = in_sizes[0] / 128;
    int E = in_sizes[1] / 2;
    const int* srcA = ei;
    const int* dstA = ei + E;

    char* ws = (char*)d_ws;
    size_t off = 0;
    auto alloc = [&](size_t bytes) {
        void* p = ws + off;
        off += (bytes + 255) & ~(size_t)255;
        return p;
    };
    float* h1     = (float*)alloc((size_t)N * 128 * 4);
    float* out1   = (float*)alloc((size_t)N * 128 * 4);
    float* h2     = (float*)alloc((size_t)N * 32 * 4);
    float* as1    = (float*)alloc((size_t)N * 4 * 4);
    float* ad1    = (float*)alloc((size_t)N * 4 * 4);
    float* as2    = (float*)alloc((size_t)N * 4);
    float* ad2    = (float*)alloc((size_t)N * 4);
    int*   rowptr = (int*)alloc((size_t)(N + 1) * 4);
    int*   cnt    = (int*)alloc((size_t)N * 4);
    int*   cursor = (int*)alloc((size_t)N * 4);
    int*   col    = (int*)alloc((size_t)(E + N) * 4);
    int nb = (N + 255) / 256;
    int*   psum   = (int*)alloc((size_t)nb * 4);

    int Etot = E + N;

    hipLaunchKernelGGL(fill_zero_i32, dim3((N + 255) / 256), dim3(256), 0, stream, cnt, N);
    hipLaunchKernelGGL(hist_kernel, dim3((Etot + 255) / 256), dim3(256), 0, stream, dstA, E, N, cnt);
    hipLaunchKernelGGL(block_sum_kernel, dim3(nb), dim3(256), 0, stream, cnt, psum, N);
    hipLaunchKernelGGL(scan_psum_kernel, dim3(1), dim3(1024), 0, stream, psum, rowptr, nb, N);
    hipLaunchKernelGGL(scan_final_kernel, dim3(nb), dim3(256), 0, stream, cnt, psum, rowptr, cursor, N);
    hipLaunchKernelGGL(scatter_kernel, dim3((Etot + 255) / 256), dim3(256), 0, stream,
                       srcA, dstA, E, N, cursor, col);
    hipLaunchKernelGGL(gemm1_kernel, dim3((N + 127) / 128), dim3(512), 0, stream,
                       x, W1, a_s1, a_d1, h1, as1, ad1, N);
    hipLaunchKernelGGL(agg1_kernel, dim3((N + 3) / 4), dim3(256), 0, stream,
                       rowptr, col, h1, as1, ad1, b1, out1, N);
    hipLaunchKernelGGL(gemm2_kernel, dim3((N + 63) / 64), dim3(256), 0, stream,
                       out1, W2, a_s2, a_d2, h2, as2, ad2, N);
    hipLaunchKernelGGL(agg2_kernel, dim3((N + 3) / 4), dim3(256), 0, stream,
                       rowptr, col, h2, as2, ad2, b2, (float*)d_out, N);
}

// Round 3
// 329.139 us; speedup vs baseline: 2.2729x; 1.4619x over previous
//
#include <hip/hip_runtime.h>
#include <math.h>

#define NEG_SLOPE 0.2f
#define EPB 8192            // edges per P1 block

// ================= generic in-place exclusive scan (3 kernels) =================

__global__ __launch_bounds__(256) void gscan_bsum(const int* __restrict__ arr,
                                                  int* __restrict__ psum, int M) {
    __shared__ int red[4];
    int tid = threadIdx.x;
    int idx = blockIdx.x * 256 + tid;
    int v = (idx < M) ? arr[idx] : 0;
    #pragma unroll
    for (int off = 1; off < 64; off <<= 1) v += __shfl_xor(v, off, 64);
    if ((tid & 63) == 0) red[tid >> 6] = v;
    __syncthreads();
    if (tid == 0) psum[blockIdx.x] = red[0] + red[1] + red[2] + red[3];
}

__global__ __launch_bounds__(1024) void gscan_psum(int* __restrict__ psum, int nb) {
    __shared__ int ws[16];
    int tid = threadIdx.x, lane = tid & 63, w = tid >> 6;
    int v = (tid < nb) ? psum[tid] : 0;
    int incl = v;
    #pragma unroll
    for (int off = 1; off < 64; off <<= 1) {
        int t = __shfl_up(incl, off, 64);
        if (lane >= off) incl += t;
    }
    if (lane == 63) ws[w] = incl;
    __syncthreads();
    int wbase = 0;
    #pragma unroll
    for (int j = 0; j < 16; j++) { if (j < w) wbase += ws[j]; }
    if (tid < nb) psum[tid] = wbase + incl - v;   // exclusive
}

__global__ __launch_bounds__(256) void gscan_final(int* __restrict__ arr,
                                                   const int* __restrict__ psum, int M) {
    __shared__ int ws[4];
    int tid = threadIdx.x, lane = tid & 63, w = tid >> 6;
    int idx = blockIdx.x * 256 + tid;
    int v = (idx < M) ? arr[idx] : 0;
    int incl = v;
    #pragma unroll
    for (int off = 1; off < 64; off <<= 1) {
        int t = __shfl_up(incl, off, 64);
        if (lane >= off) incl += t;
    }
    if (lane == 63) ws[w] = incl;
    __syncthreads();
    int wbase = 0;
    #pragma unroll
    for (int j = 0; j < 4; j++) { if (j < w) wbase += ws[j]; }
    if (idx < M) arr[idx] = psum[blockIdx.x] + wbase + incl - v;
}

// ================= CSR build: two-level counting sort, LDS atomics only =================
// bucket = dst >> 8  (nbuckets = ceil(N/256) = 391 for N=100K), local = dst & 255.

__global__ __launch_bounds__(256) void p1_hist(const int* __restrict__ dst, int E, int N,
                                               int nblk1, int nbuckets,
                                               int* __restrict__ partial) {
    __shared__ int hist[1024];
    int tid = threadIdx.x;
    for (int i = tid; i < nbuckets; i += 256) hist[i] = 0;
    __syncthreads();
    int base = blockIdx.x * EPB;
    int tot = E + N;
    #pragma unroll
    for (int it = 0; it < EPB / 256; it++) {
        int i = base + it * 256 + tid;
        if (i < tot) {
            int d = (i < E) ? dst[i] : (i - E);   // self-loops appended
            atomicAdd(&hist[d >> 8], 1);          // LDS atomic
        }
    }
    __syncthreads();
    for (int b = tid; b < nbuckets; b += 256)
        partial[b * nblk1 + blockIdx.x] = hist[b];   // bucket-major
}

__global__ __launch_bounds__(256) void p1_scatter(const int* __restrict__ src,
                                                  const int* __restrict__ dst, int E, int N,
                                                  int nblk1, int nbuckets,
                                                  const int* __restrict__ scanned,
                                                  int2* __restrict__ pairs) {
    __shared__ int cursor[1024];
    int tid = threadIdx.x;
    for (int b = tid; b < nbuckets; b += 256)
        cursor[b] = scanned[b * nblk1 + blockIdx.x];
    __syncthreads();
    int base = blockIdx.x * EPB;
    int tot = E + N;
    #pragma unroll
    for (int it = 0; it < EPB / 256; it++) {
        int i = base + it * 256 + tid;
        if (i < tot) {
            int s = (i < E) ? src[i] : (i - E);
            int d = (i < E) ? dst[i] : (i - E);
            int pos = atomicAdd(&cursor[d >> 8], 1);  // LDS atomic w/ return
            pairs[pos] = make_int2(d, s);
        }
    }
}

__global__ __launch_bounds__(256) void p2_kernel(const int2* __restrict__ pairs,
                                                 const int* __restrict__ scanned,
                                                 int nblk1, int nbuckets, int Etot, int N,
                                                 int* __restrict__ rowptr,
                                                 int* __restrict__ col) {
    __shared__ int cnt[256];
    __shared__ int cur[256];
    __shared__ int wsum[4];
    int b = blockIdx.x;
    int tid = threadIdx.x, lane = tid & 63, w = tid >> 6;
    int bucketStart = scanned[b * nblk1];
    int bucketEnd = (b + 1 < nbuckets) ? scanned[(b + 1) * nblk1] : Etot;
    cnt[tid] = 0;
    __syncthreads();
    for (int i = bucketStart + tid; i < bucketEnd; i += 256) {
        int2 p = pairs[i];
        atomicAdd(&cnt[p.x & 255], 1);
    }
    __syncthreads();
    int v = cnt[tid];
    int incl = v;
    #pragma unroll
    for (int off = 1; off < 64; off <<= 1) {
        int t = __shfl_up(incl, off, 64);
        if (lane >= off) incl += t;
    }
    if (lane == 63) wsum[w] = incl;
    __syncthreads();
    int wbase = 0;
    #pragma unroll
    for (int j = 0; j < 4; j++) { if (j < w) wbase += wsum[j]; }
    int base = bucketStart + wbase + incl - v;   // exclusive position for this local dst
    cur[tid] = base;
    int d = b * 256 + tid;
    if (d < N) rowptr[d] = base;
    if (b == nbuckets - 1 && tid == 0) rowptr[N] = Etot;
    __syncthreads();
    for (int i = bucketStart + tid; i < bucketEnd; i += 256) {
        int2 p = pairs[i];
        int pos = atomicAdd(&cur[p.x & 255], 1);
        col[pos] = p.y;
    }
}

// ---------------- Layer 1 GEMM: h1 = x @ W1 (register-tiled), plus as1/ad1 ----------------

#define XPAD 132

__global__ __launch_bounds__(512) void gemm1_kernel(const float* __restrict__ x,
                                                    const float* __restrict__ W,
                                                    const float* __restrict__ a_s,
                                                    const float* __restrict__ a_d,
                                                    float* __restrict__ h1,
                                                    float* __restrict__ as1,
                                                    float* __restrict__ ad1, int N) {
    __shared__ float xs[128 * XPAD];
    __shared__ float Ws[128 * 128];
    __shared__ float red[2 * 128 * 16];
    int tid = threadIdx.x;
    int row0 = blockIdx.x * 128;
    {
        const float4* W4 = (const float4*)W;
        float4* Ws4 = (float4*)Ws;
        #pragma unroll
        for (int it = 0; it < 8; it++) Ws4[tid + it * 512] = W4[tid + it * 512];
    }
    #pragma unroll
    for (int it = 0; it < 8; it++) {
        int i = tid + it * 512;
        int r = i >> 5, k4 = i & 31;
        int row = row0 + r;
        float4 v = (row < N) ? ((const float4*)x)[row * 32 + k4] : make_float4(0.f, 0.f, 0.f, 0.f);
        *(float4*)&xs[r * XPAD + k4 * 4] = v;
    }
    __syncthreads();

    int cc = tid & 15, rr = tid >> 4;
    float acc[4][8];
    #pragma unroll
    for (int r = 0; r < 4; r++)
        #pragma unroll
        for (int j = 0; j < 8; j++) acc[r][j] = 0.f;

    for (int k4 = 0; k4 < 32; k4++) {
        float4 xk[4];
        #pragma unroll
        for (int r = 0; r < 4; r++)
            xk[r] = *(const float4*)&xs[(rr * 4 + r) * XPAD + k4 * 4];
        #pragma unroll
        for (int kk = 0; kk < 4; kk++) {
            int k = k4 * 4 + kk;
            float4 w0 = *(const float4*)&Ws[k * 128 + cc * 8];
            float4 w1 = *(const float4*)&Ws[k * 128 + cc * 8 + 4];
            #pragma unroll
            for (int r = 0; r < 4; r++) {
                float xv = ((const float*)&xk[r])[kk];
                acc[r][0] = fmaf(xv, w0.x, acc[r][0]);
                acc[r][1] = fmaf(xv, w0.y, acc[r][1]);
                acc[r][2] = fmaf(xv, w0.z, acc[r][2]);
                acc[r][3] = fmaf(xv, w0.w, acc[r][3]);
                acc[r][4] = fmaf(xv, w1.x, acc[r][4]);
                acc[r][5] = fmaf(xv, w1.y, acc[r][5]);
                acc[r][6] = fmaf(xv, w1.z, acc[r][6]);
                acc[r][7] = fmaf(xv, w1.w, acc[r][7]);
            }
        }
    }

    #pragma unroll
    for (int r = 0; r < 4; r++) {
        float sd = 0.f, dd = 0.f;
        #pragma unroll
        for (int j = 0; j < 8; j++) {
            sd = fmaf(acc[r][j], a_s[cc * 8 + j], sd);
            dd = fmaf(acc[r][j], a_d[cc * 8 + j], dd);
        }
        red[(rr * 4 + r) * 16 + cc] = sd;
        red[2048 + (rr * 4 + r) * 16 + cc] = dd;
    }
    #pragma unroll
    for (int r = 0; r < 4; r++) {
        int row = row0 + rr * 4 + r;
        if (row < N) {
            *(float4*)&h1[row * 128 + cc * 8]     = make_float4(acc[r][0], acc[r][1], acc[r][2], acc[r][3]);
            *(float4*)&h1[row * 128 + cc * 8 + 4] = make_float4(acc[r][4], acc[r][5], acc[r][6], acc[r][7]);
        }
    }
    __syncthreads();
    {
        int row = tid >> 2, h = tid & 3;
        if (row0 + row < N) {
            float s = red[row * 16 + h * 4] + red[row * 16 + h * 4 + 1] +
                      red[row * 16 + h * 4 + 2] + red[row * 16 + h * 4 + 3];
            float d = red[2048 + row * 16 + h * 4] + red[2048 + row * 16 + h * 4 + 1] +
                      red[2048 + row * 16 + h * 4 + 2] + red[2048 + row * 16 + h * 4 + 3];
            as1[(row0 + row) * 4 + h] = s;
            ad1[(row0 + row) * 4 + h] = d;
        }
    }
}

// ---------------- Layer 1 aggregation ----------------

__device__ __forceinline__ float sel4(float4 a, int h) {
    return h < 2 ? (h == 0 ? a.x : a.y) : (h == 2 ? a.z : a.w);
}

__global__ __launch_bounds__(256) void agg1_kernel(const int* __restrict__ rowptr,
                                                   const int* __restrict__ col,
                                                   const float* __restrict__ h1,
                                                   const float* __restrict__ as1,
                                                   const float* __restrict__ ad1,
                                                   const float* __restrict__ b1,
                                                   float* __restrict__ out1, int N) {
    int lane = threadIdx.x & 63;
    int wid = __builtin_amdgcn_readfirstlane(threadIdx.x >> 6);
    int n = blockIdx.x * 4 + wid;
    if (n >= N) return;
    int hh = lane >> 4;
    const float4* as4 = (const float4*)as1;
    const float2* h1v = (const float2*)h1;
    float adn = sel4(((const float4*)ad1)[n], hh);
    int beg = rowptr[n], end = rowptr[n + 1];
    float ax = 0.f, ay = 0.f, den = 0.f;
    int i = beg;
    for (; i + 4 <= end; i += 4) {
        int s0 = col[i], s1 = col[i + 1], s2 = col[i + 2], s3 = col[i + 3];
        float4 A0 = as4[s0], A1 = as4[s1], A2 = as4[s2], A3 = as4[s3];
        float2 v0 = h1v[s0 * 64 + lane];
        float2 v1 = h1v[s1 * 64 + lane];
        float2 v2 = h1v[s2 * 64 + lane];
        float2 v3 = h1v[s3 * 64 + lane];
        float e0 = sel4(A0, hh) + adn;
        float e1 = sel4(A1, hh) + adn;
        float e2 = sel4(A2, hh) + adn;
        float e3 = sel4(A3, hh) + adn;
        e0 = fmaxf(e0, e0 * NEG_SLOPE);
        e1 = fmaxf(e1, e1 * NEG_SLOPE);
        e2 = fmaxf(e2, e2 * NEG_SLOPE);
        e3 = fmaxf(e3, e3 * NEG_SLOPE);
        float ex0 = __expf(e0), ex1 = __expf(e1), ex2 = __expf(e2), ex3 = __expf(e3);
        den += ex0 + ex1 + ex2 + ex3;
        ax = fmaf(ex0, v0.x, ax); ay = fmaf(ex0, v0.y, ay);
        ax = fmaf(ex1, v1.x, ax); ay = fmaf(ex1, v1.y, ay);
        ax = fmaf(ex2, v2.x, ax); ay = fmaf(ex2, v2.y, ay);
        ax = fmaf(ex3, v3.x, ax); ay = fmaf(ex3, v3.y, ay);
    }
    for (; i < end; i++) {
        int s = col[i];
        float2 v = h1v[s * 64 + lane];
        float e = sel4(as4[s], hh) + adn;
        e = fmaxf(e, e * NEG_SLOPE);
        float ex = __expf(e);
        den += ex;
        ax = fmaf(ex, v.x, ax); ay = fmaf(ex, v.y, ay);
    }
    float2 bb = ((const float2*)b1)[lane];
    float2 o;
    o.x = fmaxf(ax / den + bb.x, 0.f);
    o.y = fmaxf(ay / den + bb.y, 0.f);
    ((float2*)out1)[n * 64 + lane] = o;
}

// ---------------- Layer 2 GEMM ----------------

__global__ __launch_bounds__(256) void gemm2_kernel(const float* __restrict__ xin,
                                                    const float* __restrict__ W,
                                                    const float* __restrict__ a_s,
                                                    const float* __restrict__ a_d,
                                                    float* __restrict__ h2,
                                                    float* __restrict__ as2,
                                                    float* __restrict__ ad2, int N) {
    __shared__ float Ws[128 * 32];
    __shared__ float xs[64 * 129];
    __shared__ float red[64 * 8];
    int tid = threadIdx.x;
    {
        const float4* W4 = (const float4*)W;
        float4* Ws4 = (float4*)Ws;
        #pragma unroll
        for (int it = 0; it < 4; it++) Ws4[tid + it * 256] = W4[tid + it * 256];
    }
    int row0 = blockIdx.x * 64;
    #pragma unroll
    for (int it = 0; it < 8; it++) {
        int i = tid + it * 256;
        int r = i >> 5, k4 = i & 31;
        int row = row0 + r;
        float4 v = (row < N) ? ((const float4*)xin)[row * 32 + k4] : make_float4(0.f, 0.f, 0.f, 0.f);
        *(float4*)&xs[r * 129 + k4 * 4] = v;
    }
    __syncthreads();

    int r = tid & 63, g = tid >> 6;
    float acc[8];
    #pragma unroll
    for (int j = 0; j < 8; j++) acc[j] = 0.f;
    for (int k = 0; k < 128; k++) {
        float xv = xs[r * 129 + k];
        const float* w = &Ws[k * 32 + g * 8];
        #pragma unroll
        for (int j = 0; j < 8; j++) acc[j] = fmaf(xv, w[j], acc[j]);
    }

    float sd = 0.f, dd = 0.f;
    #pragma unroll
    for (int j = 0; j < 8; j++) {
        sd = fmaf(acc[j], a_s[g * 8 + j], sd);
        dd = fmaf(acc[j], a_d[g * 8 + j], dd);
    }
    red[r * 8 + g] = sd;
    red[r * 8 + 4 + g] = dd;
    int row = row0 + r;
    if (row < N) {
        float4* o = (float4*)&h2[row * 32 + g * 8];
        o[0] = make_float4(acc[0], acc[1], acc[2], acc[3]);
        o[1] = make_float4(acc[4], acc[5], acc[6], acc[7]);
    }
    __syncthreads();
    if (tid < 64 && row0 + tid < N) {
        as2[row0 + tid] = red[tid * 8 + 0] + red[tid * 8 + 1] + red[tid * 8 + 2] + red[tid * 8 + 3];
        ad2[row0 + tid] = red[tid * 8 + 4] + red[tid * 8 + 5] + red[tid * 8 + 6] + red[tid * 8 + 7];
    }
}

// ---------------- Layer 2 aggregation ----------------

__global__ __launch_bounds__(256) void agg2_kernel(const int* __restrict__ rowptr,
                                                   const int* __restrict__ col,
                                                   const float* __restrict__ h2,
                                                   const float* __restrict__ as2,
                                                   const float* __restrict__ ad2,
                                                   const float* __restrict__ b2,
                                                   float* __restrict__ out, int N) {
    int lane = threadIdx.x & 63;
    int wid = __builtin_amdgcn_readfirstlane(threadIdx.x >> 6);
    int n = blockIdx.x * 4 + wid;
    if (n >= N) return;
    int half = lane >> 5, c = lane & 31;
    float adn = ad2[n];
    int beg = rowptr[n], end = rowptr[n + 1];
    float acc = 0.f, den = 0.f;
    int i = beg;
    for (; i + 8 <= end; i += 8) {
        int s0 = col[i + half];
        int s1 = col[i + 2 + half];
        int s2 = col[i + 4 + half];
        int s3 = col[i + 6 + half];
        float a0 = as2[s0], a1 = as2[s1], a2 = as2[s2], a3 = as2[s3];
        float v0 = h2[s0 * 32 + c], v1 = h2[s1 * 32 + c];
        float v2 = h2[s2 * 32 + c], v3 = h2[s3 * 32 + c];
        float e0 = a0 + adn, e1 = a1 + adn, e2 = a2 + adn, e3 = a3 + adn;
        e0 = fmaxf(e0, e0 * NEG_SLOPE);
        e1 = fmaxf(e1, e1 * NEG_SLOPE);
        e2 = fmaxf(e2, e2 * NEG_SLOPE);
        e3 = fmaxf(e3, e3 * NEG_SLOPE);
        float ex0 = __expf(e0), ex1 = __expf(e1), ex2 = __expf(e2), ex3 = __expf(e3);
        den += ex0 + ex1 + ex2 + ex3;
        acc = fmaf(ex0, v0, acc);
        acc = fmaf(ex1, v1, acc);
        acc = fmaf(ex2, v2, acc);
        acc = fmaf(ex3, v3, acc);
    }
    for (; i + 2 <= end; i += 2) {
        int s = col[i + half];
        float e = as2[s] + adn;
        e = fmaxf(e, e * NEG_SLOPE);
        float ex = __expf(e);
        den += ex;
        acc = fmaf(ex, h2[s * 32 + c], acc);
    }
    if (i < end && half == 0) {
        int s = col[i];
        float e = as2[s] + adn;
        e = fmaxf(e, e * NEG_SLOPE);
        float ex = __expf(e);
        den += ex;
        acc = fmaf(ex, h2[s * 32 + c], acc);
    }
    den += __shfl_xor(den, 32, 64);
    acc += __shfl_xor(acc, 32, 64);
    if (half == 0) out[n * 32 + c] = acc / den + b2[c];
}

// ---------------- launch ----------------

extern "C" void kernel_launch(void* const* d_in, const int* in_sizes, int n_in,
                              void* d_out, int out_size, void* d_ws, size_t ws_size,
                              hipStream_t stream) {
    const float* x    = (const float*)d_in[0];
    const int*   ei   = (const int*)d_in[1];
    const float* W1   = (const float*)d_in[2];
    const float* a_s1 = (const float*)d_in[3];
    const float* a_d1 = (const float*)d_in[4];
    const float* b1   = (const float*)d_in[5];
    const float* W2   = (const float*)d_in[6];
    const float* a_s2 = (const float*)d_in[7];
    const float* a_d2 = (const float*)d_in[8];
    const float* b2   = (const float*)d_in[9];

    int N = in_sizes[0] / 128;
    int E = in_sizes[1] / 2;
    const int* srcA = ei;
    const int* dstA = ei + E;
    int Etot = E + N;

    char* ws = (char*)d_ws;
    size_t off = 0;
    auto alloc = [&](size_t bytes) {
        void* p = ws + off;
        off += (bytes + 255) & ~(size_t)255;
        return p;
    };
    float* h1     = (float*)alloc((size_t)N * 128 * 4);
    float* out1   = (float*)alloc((size_t)N * 128 * 4);
    float* h2     = (float*)alloc((size_t)N * 32 * 4);
    float* as1    = (float*)alloc((size_t)N * 4 * 4);
    float* ad1    = (float*)alloc((size_t)N * 4 * 4);
    float* as2    = (float*)alloc((size_t)N * 4);
    float* ad2    = (float*)alloc((size_t)N * 4);
    int*   rowptr = (int*)alloc((size_t)(N + 1) * 4);
    int*   col    = (int*)alloc((size_t)Etot * 4);
    int2*  pairs  = (int2*)alloc((size_t)Etot * 8);

    int nbuckets = (N + 255) >> 8;                 // 391
    int nblk1 = (Etot + EPB - 1) / EPB;            // 208
    int M = nbuckets * nblk1;                      // ~81K
    int*   partial = (int*)alloc((size_t)M * 4);
    int nbs = (M + 255) / 256;                     // 318 (<=1024)
    int*   psum    = (int*)alloc((size_t)1024 * 4);

    // CSR build (LDS-atomic two-level counting sort)
    hipLaunchKernelGGL(p1_hist, dim3(nblk1), dim3(256), 0, stream,
                       dstA, E, N, nblk1, nbuckets, partial);
    hipLaunchKernelGGL(gscan_bsum, dim3(nbs), dim3(256), 0, stream, partial, psum, M);
    hipLaunchKernelGGL(gscan_psum, dim3(1), dim3(1024), 0, stream, psum, nbs);
    hipLaunchKernelGGL(gscan_final, dim3(nbs), dim3(256), 0, stream, partial, psum, M);
    hipLaunchKernelGGL(p1_scatter, dim3(nblk1), dim3(256), 0, stream,
                       srcA, dstA, E, N, nblk1, nbuckets, partial, pairs);
    hipLaunchKernelGGL(p2_kernel, dim3(nbuckets), dim3(256), 0, stream,
                       pairs, partial, nblk1, nbuckets, Etot, N, rowptr, col);

    // GAT layers
    hipLaunchKernelGGL(gemm1_kernel, dim3((N + 127) / 128), dim3(512), 0, stream,
                       x, W1, a_s1, a_d1, h1, as1, ad1, N);
    hipLaunchKernelGGL(agg1_kernel, dim3((N + 3) / 4), dim3(256), 0, stream,
                       rowptr, col, h1, as1, ad1, b1, out1, N);
    hipLaunchKernelGGL(gemm2_kernel, dim3((N + 63) / 64), dim3(256), 0, stream,
                       out1, W2, a_s2, a_d2, h2, as2, ad2, N);
    hipLaunchKernelGGL(agg2_kernel, dim3((N + 3) / 4), dim3(256), 0, stream,
                       rowptr, col, h2, as2, ad2, b2, (float*)d_out, N);
}

// Round 4
// 289.863 us; speedup vs baseline: 2.5809x; 1.1355x over previous
//
#include <hip/hip_runtime.h>
#include <math.h>

#define NEG_SLOPE 0.2f
#define EPB 8192            // edges per P1 block

__device__ __forceinline__ unsigned pack_bf16x2(float a, float b) {
    unsigned ua = __float_as_uint(a);
    unsigned ub = __float_as_uint(b);
    ua += 0x7FFFu + ((ua >> 16) & 1u);     // RNE
    ub += 0x7FFFu + ((ub >> 16) & 1u);
    return (ua >> 16) | (ub & 0xFFFF0000u);
}
__device__ __forceinline__ float bf_lo(unsigned u) { return __uint_as_float(u << 16); }
__device__ __forceinline__ float bf_hi(unsigned u) { return __uint_as_float(u & 0xFFFF0000u); }

// ================= generic in-place exclusive scan (3 kernels) =================

__global__ __launch_bounds__(256) void gscan_bsum(const int* __restrict__ arr,
                                                  int* __restrict__ psum, int M) {
    __shared__ int red[4];
    int tid = threadIdx.x;
    int idx = blockIdx.x * 256 + tid;
    int v = (idx < M) ? arr[idx] : 0;
    #pragma unroll
    for (int off = 1; off < 64; off <<= 1) v += __shfl_xor(v, off, 64);
    if ((tid & 63) == 0) red[tid >> 6] = v;
    __syncthreads();
    if (tid == 0) psum[blockIdx.x] = red[0] + red[1] + red[2] + red[3];
}

__global__ __launch_bounds__(1024) void gscan_psum(int* __restrict__ psum, int nb) {
    __shared__ int ws[16];
    int tid = threadIdx.x, lane = tid & 63, w = tid >> 6;
    int v = (tid < nb) ? psum[tid] : 0;
    int incl = v;
    #pragma unroll
    for (int off = 1; off < 64; off <<= 1) {
        int t = __shfl_up(incl, off, 64);
        if (lane >= off) incl += t;
    }
    if (lane == 63) ws[w] = incl;
    __syncthreads();
    int wbase = 0;
    #pragma unroll
    for (int j = 0; j < 16; j++) { if (j < w) wbase += ws[j]; }
    if (tid < nb) psum[tid] = wbase + incl - v;   // exclusive
}

__global__ __launch_bounds__(256) void gscan_final(int* __restrict__ arr,
                                                   const int* __restrict__ psum, int M) {
    __shared__ int ws[4];
    int tid = threadIdx.x, lane = tid & 63, w = tid >> 6;
    int idx = blockIdx.x * 256 + tid;
    int v = (idx < M) ? arr[idx] : 0;
    int incl = v;
    #pragma unroll
    for (int off = 1; off < 64; off <<= 1) {
        int t = __shfl_up(incl, off, 64);
        if (lane >= off) incl += t;
    }
    if (lane == 63) ws[w] = incl;
    __syncthreads();
    int wbase = 0;
    #pragma unroll
    for (int j = 0; j < 4; j++) { if (j < w) wbase += ws[j]; }
    if (idx < M) arr[idx] = psum[blockIdx.x] + wbase + incl - v;
}

// ================= CSR build: two-level counting sort, LDS atomics only =================
// bucket = dst >> 8; pair packed as (local_dst<<24) | src  (src < 2^24).

__global__ __launch_bounds__(256) void p1_hist(const int* __restrict__ dst, int E, int N,
                                               int nblk1, int nbuckets,
                                               int* __restrict__ partial) {
    __shared__ int hist[1024];
    int tid = threadIdx.x;
    for (int i = tid; i < nbuckets; i += 256) hist[i] = 0;
    __syncthreads();
    int base = blockIdx.x * EPB;
    int tot = E + N;
    #pragma unroll
    for (int it = 0; it < EPB / 256; it++) {
        int i = base + it * 256 + tid;
        if (i < tot) {
            int d = (i < E) ? dst[i] : (i - E);   // self-loops appended
            atomicAdd(&hist[d >> 8], 1);          // LDS atomic
        }
    }
    __syncthreads();
    for (int b = tid; b < nbuckets; b += 256)
        partial[b * nblk1 + blockIdx.x] = hist[b];   // bucket-major
}

__global__ __launch_bounds__(256) void p1_scatter(const int* __restrict__ src,
                                                  const int* __restrict__ dst, int E, int N,
                                                  int nblk1, int nbuckets,
                                                  const int* __restrict__ scanned,
                                                  unsigned* __restrict__ pairs) {
    __shared__ int cursor[1024];
    int tid = threadIdx.x;
    for (int b = tid; b < nbuckets; b += 256)
        cursor[b] = scanned[b * nblk1 + blockIdx.x];
    __syncthreads();
    int base = blockIdx.x * EPB;
    int tot = E + N;
    #pragma unroll
    for (int it = 0; it < EPB / 256; it++) {
        int i = base + it * 256 + tid;
        if (i < tot) {
            int s = (i < E) ? src[i] : (i - E);
            int d = (i < E) ? dst[i] : (i - E);
            int pos = atomicAdd(&cursor[d >> 8], 1);  // LDS atomic w/ return
            pairs[pos] = ((unsigned)(d & 255) << 24) | (unsigned)s;
        }
    }
}

__global__ __launch_bounds__(256) void p2_kernel(const unsigned* __restrict__ pairs,
                                                 const int* __restrict__ scanned,
                                                 int nblk1, int nbuckets, int Etot, int N,
                                                 int* __restrict__ rowptr,
                                                 int* __restrict__ col) {
    __shared__ int cnt[256];
    __shared__ int cur[256];
    __shared__ int wsum[4];
    int b = blockIdx.x;
    int tid = threadIdx.x, lane = tid & 63, w = tid >> 6;
    int bucketStart = scanned[b * nblk1];
    int bucketEnd = (b + 1 < nbuckets) ? scanned[(b + 1) * nblk1] : Etot;
    cnt[tid] = 0;
    __syncthreads();
    for (int i = bucketStart + tid; i < bucketEnd; i += 256) {
        unsigned p = pairs[i];
        atomicAdd(&cnt[p >> 24], 1);
    }
    __syncthreads();
    int v = cnt[tid];
    int incl = v;
    #pragma unroll
    for (int off = 1; off < 64; off <<= 1) {
        int t = __shfl_up(incl, off, 64);
        if (lane >= off) incl += t;
    }
    if (lane == 63) wsum[w] = incl;
    __syncthreads();
    int wbase = 0;
    #pragma unroll
    for (int j = 0; j < 4; j++) { if (j < w) wbase += wsum[j]; }
    int base = bucketStart + wbase + incl - v;   // exclusive position for this local dst
    cur[tid] = base;
    int d = b * 256 + tid;
    if (d < N) rowptr[d] = base;
    if (b == nbuckets - 1 && tid == 0) rowptr[N] = Etot;
    __syncthreads();
    for (int i = bucketStart + tid; i < bucketEnd; i += 256) {
        unsigned p = pairs[i];
        int pos = atomicAdd(&cur[p >> 24], 1);
        col[pos] = (int)(p & 0xFFFFFFu);
    }
}

// ---------------- Layer 1 GEMM: h1(bf16) = x @ W1, plus as1/ad1 (fp32) ----------------

#define XPAD 132

__global__ __launch_bounds__(512) void gemm1_kernel(const float* __restrict__ x,
                                                    const float* __restrict__ W,
                                                    const float* __restrict__ a_s,
                                                    const float* __restrict__ a_d,
                                                    unsigned* __restrict__ h1b,
                                                    float* __restrict__ as1,
                                                    float* __restrict__ ad1, int N) {
    __shared__ float xs[128 * XPAD];
    __shared__ float Ws[128 * 128];
    __shared__ float red[2 * 128 * 16];
    int tid = threadIdx.x;
    int row0 = blockIdx.x * 128;
    {
        const float4* W4 = (const float4*)W;
        float4* Ws4 = (float4*)Ws;
        #pragma unroll
        for (int it = 0; it < 8; it++) Ws4[tid + it * 512] = W4[tid + it * 512];
    }
    #pragma unroll
    for (int it = 0; it < 8; it++) {
        int i = tid + it * 512;
        int r = i >> 5, k4 = i & 31;
        int row = row0 + r;
        float4 v = (row < N) ? ((const float4*)x)[row * 32 + k4] : make_float4(0.f, 0.f, 0.f, 0.f);
        *(float4*)&xs[r * XPAD + k4 * 4] = v;
    }
    __syncthreads();

    int cc = tid & 15, rr = tid >> 4;
    float acc[4][8];
    #pragma unroll
    for (int r = 0; r < 4; r++)
        #pragma unroll
        for (int j = 0; j < 8; j++) acc[r][j] = 0.f;

    for (int k4 = 0; k4 < 32; k4++) {
        float4 xk[4];
        #pragma unroll
        for (int r = 0; r < 4; r++)
            xk[r] = *(const float4*)&xs[(rr * 4 + r) * XPAD + k4 * 4];
        #pragma unroll
        for (int kk = 0; kk < 4; kk++) {
            int k = k4 * 4 + kk;
            float4 w0 = *(const float4*)&Ws[k * 128 + cc * 8];
            float4 w1 = *(const float4*)&Ws[k * 128 + cc * 8 + 4];
            #pragma unroll
            for (int r = 0; r < 4; r++) {
                float xv = ((const float*)&xk[r])[kk];
                acc[r][0] = fmaf(xv, w0.x, acc[r][0]);
                acc[r][1] = fmaf(xv, w0.y, acc[r][1]);
                acc[r][2] = fmaf(xv, w0.z, acc[r][2]);
                acc[r][3] = fmaf(xv, w0.w, acc[r][3]);
                acc[r][4] = fmaf(xv, w1.x, acc[r][4]);
                acc[r][5] = fmaf(xv, w1.y, acc[r][5]);
                acc[r][6] = fmaf(xv, w1.z, acc[r][6]);
                acc[r][7] = fmaf(xv, w1.w, acc[r][7]);
            }
        }
    }

    #pragma unroll
    for (int r = 0; r < 4; r++) {
        float sd = 0.f, dd = 0.f;
        #pragma unroll
        for (int j = 0; j < 8; j++) {
            sd = fmaf(acc[r][j], a_s[cc * 8 + j], sd);
            dd = fmaf(acc[r][j], a_d[cc * 8 + j], dd);
        }
        red[(rr * 4 + r) * 16 + cc] = sd;
        red[2048 + (rr * 4 + r) * 16 + cc] = dd;
    }
    #pragma unroll
    for (int r = 0; r < 4; r++) {
        int row = row0 + rr * 4 + r;
        if (row < N) {
            uint4 pk;
            pk.x = pack_bf16x2(acc[r][0], acc[r][1]);
            pk.y = pack_bf16x2(acc[r][2], acc[r][3]);
            pk.z = pack_bf16x2(acc[r][4], acc[r][5]);
            pk.w = pack_bf16x2(acc[r][6], acc[r][7]);
            *(uint4*)&h1b[row * 64 + cc * 4] = pk;
        }
    }
    __syncthreads();
    {
        int row = tid >> 2, h = tid & 3;
        if (row0 + row < N) {
            float s = red[row * 16 + h * 4] + red[row * 16 + h * 4 + 1] +
                      red[row * 16 + h * 4 + 2] + red[row * 16 + h * 4 + 3];
            float d = red[2048 + row * 16 + h * 4] + red[2048 + row * 16 + h * 4 + 1] +
                      red[2048 + row * 16 + h * 4 + 2] + red[2048 + row * 16 + h * 4 + 3];
            as1[(row0 + row) * 4 + h] = s;
            ad1[(row0 + row) * 4 + h] = d;
        }
    }
}

// ---------------- Layer 1 aggregation: bf16 h1 gather (4B/lane), fp32 math ----------------

__device__ __forceinline__ float sel4(float4 a, int h) {
    return h < 2 ? (h == 0 ? a.x : a.y) : (h == 2 ? a.z : a.w);
}

__global__ __launch_bounds__(256) void agg1_kernel(const int* __restrict__ rowptr,
                                                   const int* __restrict__ col,
                                                   const unsigned* __restrict__ h1b,
                                                   const float* __restrict__ as1,
                                                   const float* __restrict__ ad1,
                                                   const float* __restrict__ b1,
                                                   float* __restrict__ out1, int N) {
    int lane = threadIdx.x & 63;
    int wid = __builtin_amdgcn_readfirstlane(threadIdx.x >> 6);
    int n = blockIdx.x * 4 + wid;
    if (n >= N) return;
    int hh = lane >> 4;                  // head of channels 2*lane, 2*lane+1
    const float4* as4 = (const float4*)as1;
    float adn = sel4(((const float4*)ad1)[n], hh);
    int beg = rowptr[n], end = rowptr[n + 1];
    float ax = 0.f, ay = 0.f, den = 0.f;
    int i = beg;
    for (; i + 4 <= end; i += 4) {
        int s0 = col[i], s1 = col[i + 1], s2 = col[i + 2], s3 = col[i + 3];
        float4 A0 = as4[s0], A1 = as4[s1], A2 = as4[s2], A3 = as4[s3];
        unsigned u0 = h1b[s0 * 64 + lane];
        unsigned u1 = h1b[s1 * 64 + lane];
        unsigned u2 = h1b[s2 * 64 + lane];
        unsigned u3 = h1b[s3 * 64 + lane];
        float e0 = sel4(A0, hh) + adn;
        float e1 = sel4(A1, hh) + adn;
        float e2 = sel4(A2, hh) + adn;
        float e3 = sel4(A3, hh) + adn;
        e0 = fmaxf(e0, e0 * NEG_SLOPE);
        e1 = fmaxf(e1, e1 * NEG_SLOPE);
        e2 = fmaxf(e2, e2 * NEG_SLOPE);
        e3 = fmaxf(e3, e3 * NEG_SLOPE);
        float ex0 = __expf(e0), ex1 = __expf(e1), ex2 = __expf(e2), ex3 = __expf(e3);
        den += ex0 + ex1 + ex2 + ex3;
        ax = fmaf(ex0, bf_lo(u0), ax); ay = fmaf(ex0, bf_hi(u0), ay);
        ax = fmaf(ex1, bf_lo(u1), ax); ay = fmaf(ex1, bf_hi(u1), ay);
        ax = fmaf(ex2, bf_lo(u2), ax); ay = fmaf(ex2, bf_hi(u2), ay);
        ax = fmaf(ex3, bf_lo(u3), ax); ay = fmaf(ex3, bf_hi(u3), ay);
    }
    for (; i < end; i++) {
        int s = col[i];
        unsigned u = h1b[s * 64 + lane];
        float e = sel4(as4[s], hh) + adn;
        e = fmaxf(e, e * NEG_SLOPE);
        float ex = __expf(e);
        den += ex;
        ax = fmaf(ex, bf_lo(u), ax); ay = fmaf(ex, bf_hi(u), ay);
    }
    float2 bb = ((const float2*)b1)[lane];
    float2 o;
    o.x = fmaxf(ax / den + bb.x, 0.f);
    o.y = fmaxf(ay / den + bb.y, 0.f);
    ((float2*)out1)[n * 64 + lane] = o;
}

// ---------------- Layer 2 GEMM: h2(bf16) = relu_h @ W2, plus as2/ad2 ----------------

__global__ __launch_bounds__(256) void gemm2_kernel(const float* __restrict__ xin,
                                                    const float* __restrict__ W,
                                                    const float* __restrict__ a_s,
                                                    const float* __restrict__ a_d,
                                                    unsigned* __restrict__ h2b,
                                                    float* __restrict__ as2,
                                                    float* __restrict__ ad2, int N) {
    __shared__ float Ws[128 * 32];
    __shared__ float xs[64 * 129];
    __shared__ float red[64 * 8];
    int tid = threadIdx.x;
    {
        const float4* W4 = (const float4*)W;
        float4* Ws4 = (float4*)Ws;
        #pragma unroll
        for (int it = 0; it < 4; it++) Ws4[tid + it * 256] = W4[tid + it * 256];
    }
    int row0 = blockIdx.x * 64;
    #pragma unroll
    for (int it = 0; it < 8; it++) {
        int i = tid + it * 256;
        int r = i >> 5, k4 = i & 31;
        int row = row0 + r;
        float4 v = (row < N) ? ((const float4*)xin)[row * 32 + k4] : make_float4(0.f, 0.f, 0.f, 0.f);
        *(float4*)&xs[r * 129 + k4 * 4] = v;
    }
    __syncthreads();

    int r = tid & 63, g = tid >> 6;
    float acc[8];
    #pragma unroll
    for (int j = 0; j < 8; j++) acc[j] = 0.f;
    for (int k = 0; k < 128; k++) {
        float xv = xs[r * 129 + k];
        const float* w = &Ws[k * 32 + g * 8];
        #pragma unroll
        for (int j = 0; j < 8; j++) acc[j] = fmaf(xv, w[j], acc[j]);
    }

    float sd = 0.f, dd = 0.f;
    #pragma unroll
    for (int j = 0; j < 8; j++) {
        sd = fmaf(acc[j], a_s[g * 8 + j], sd);
        dd = fmaf(acc[j], a_d[g * 8 + j], dd);
    }
    red[r * 8 + g] = sd;
    red[r * 8 + 4 + g] = dd;
    int row = row0 + r;
    if (row < N) {
        uint4 pk;
        pk.x = pack_bf16x2(acc[0], acc[1]);
        pk.y = pack_bf16x2(acc[2], acc[3]);
        pk.z = pack_bf16x2(acc[4], acc[5]);
        pk.w = pack_bf16x2(acc[6], acc[7]);
        *(uint4*)&h2b[row * 16 + g * 4] = pk;
    }
    __syncthreads();
    if (tid < 64 && row0 + tid < N) {
        as2[row0 + tid] = red[tid * 8 + 0] + red[tid * 8 + 1] + red[tid * 8 + 2] + red[tid * 8 + 3];
        ad2[row0 + tid] = red[tid * 8 + 4] + red[tid * 8 + 5] + red[tid * 8 + 6] + red[tid * 8 + 7];
    }
}

// ---------------- Layer 2 aggregation: 4 edges/wave, 16 lanes x 2 bf16 ch each ----------------

__global__ __launch_bounds__(256) void agg2_kernel(const int* __restrict__ rowptr,
                                                   const int* __restrict__ col,
                                                   const unsigned* __restrict__ h2b,
                                                   const float* __restrict__ as2,
                                                   const float* __restrict__ ad2,
                                                   const float* __restrict__ b2,
                                                   float* __restrict__ out, int N) {
    int lane = threadIdx.x & 63;
    int wid = __builtin_amdgcn_readfirstlane(threadIdx.x >> 6);
    int n = blockIdx.x * 4 + wid;
    if (n >= N) return;
    int q = lane >> 4, c2 = lane & 15;
    float adn = ad2[n];
    int beg = rowptr[n], end = rowptr[n + 1];
    float a0 = 0.f, a1 = 0.f, den = 0.f;
    int i = beg;
    for (; i + 8 <= end; i += 8) {
        int sA = col[i + q];
        int sB = col[i + 4 + q];
        float lA = as2[sA], lB = as2[sB];
        unsigned uA = h2b[sA * 16 + c2];
        unsigned uB = h2b[sB * 16 + c2];
        float eA = lA + adn, eB = lB + adn;
        eA = fmaxf(eA, eA * NEG_SLOPE);
        eB = fmaxf(eB, eB * NEG_SLOPE);
        float exA = __expf(eA), exB = __expf(eB);
        den += exA + exB;
        a0 = fmaf(exA, bf_lo(uA), a0); a1 = fmaf(exA, bf_hi(uA), a1);
        a0 = fmaf(exB, bf_lo(uB), a0); a1 = fmaf(exB, bf_hi(uB), a1);
    }
    for (; i < end; i += 4) {
        int idx = i + q;
        if (idx < end) {
            int s = col[idx];
            unsigned u = h2b[s * 16 + c2];
            float e = as2[s] + adn;
            e = fmaxf(e, e * NEG_SLOPE);
            float ex = __expf(e);
            den += ex;
            a0 = fmaf(ex, bf_lo(u), a0); a1 = fmaf(ex, bf_hi(u), a1);
        }
    }
    den += __shfl_xor(den, 16, 64);
    den += __shfl_xor(den, 32, 64);
    a0 += __shfl_xor(a0, 16, 64);
    a0 += __shfl_xor(a0, 32, 64);
    a1 += __shfl_xor(a1, 16, 64);
    a1 += __shfl_xor(a1, 32, 64);
    if (q == 0) {
        float2 bb = ((const float2*)b2)[c2];
        ((float2*)out)[n * 16 + c2] = make_float2(a0 / den + bb.x, a1 / den + bb.y);
    }
}

// ---------------- launch ----------------

extern "C" void kernel_launch(void* const* d_in, const int* in_sizes, int n_in,
                              void* d_out, int out_size, void* d_ws, size_t ws_size,
                              hipStream_t stream) {
    const float* x    = (const float*)d_in[0];
    const int*   ei   = (const int*)d_in[1];
    const float* W1   = (const float*)d_in[2];
    const float* a_s1 = (const float*)d_in[3];
    const float* a_d1 = (const float*)d_in[4];
    const float* b1   = (const float*)d_in[5];
    const float* W2   = (const float*)d_in[6];
    const float* a_s2 = (const float*)d_in[7];
    const float* a_d2 = (const float*)d_in[8];
    const float* b2   = (const float*)d_in[9];

    int N = in_sizes[0] / 128;
    int E = in_sizes[1] / 2;
    const int* srcA = ei;
    const int* dstA = ei + E;
    int Etot = E + N;

    char* ws = (char*)d_ws;
    size_t off = 0;
    auto alloc = [&](size_t bytes) {
        void* p = ws + off;
        off += (bytes + 255) & ~(size_t)255;
        return p;
    };
    unsigned* h1b  = (unsigned*)alloc((size_t)N * 128 * 2);
    float* out1    = (float*)alloc((size_t)N * 128 * 4);
    unsigned* h2b  = (unsigned*)alloc((size_t)N * 32 * 2);
    float* as1     = (float*)alloc((size_t)N * 4 * 4);
    float* ad1     = (float*)alloc((size_t)N * 4 * 4);
    float* as2     = (float*)alloc((size_t)N * 4);
    float* ad2     = (float*)alloc((size_t)N * 4);
    int*   rowptr  = (int*)alloc((size_t)(N + 1) * 4);
    int*   col     = (int*)alloc((size_t)Etot * 4);
    unsigned* pairs = (unsigned*)alloc((size_t)Etot * 4);

    int nbuckets = (N + 255) >> 8;                 // 391
    int nblk1 = (Etot + EPB - 1) / EPB;            // 208
    int M = nbuckets * nblk1;
    int*   partial = (int*)alloc((size_t)M * 4);
    int nbs = (M + 255) / 256;
    int*   psum    = (int*)alloc((size_t)1024 * 4);

    // CSR build (LDS-atomic two-level counting sort)
    hipLaunchKernelGGL(p1_hist, dim3(nblk1), dim3(256), 0, stream,
                       dstA, E, N, nblk1, nbuckets, partial);
    hipLaunchKernelGGL(gscan_bsum, dim3(nbs), dim3(256), 0, stream, partial, psum, M);
    hipLaunchKernelGGL(gscan_psum, dim3(1), dim3(1024), 0, stream, psum, nbs);
    hipLaunchKernelGGL(gscan_final, dim3(nbs), dim3(256), 0, stream, partial, psum, M);
    hipLaunchKernelGGL(p1_scatter, dim3(nblk1), dim3(256), 0, stream,
                       srcA, dstA, E, N, nblk1, nbuckets, partial, pairs);
    hipLaunchKernelGGL(p2_kernel, dim3(nbuckets), dim3(256), 0, stream,
                       pairs, partial, nblk1, nbuckets, Etot, N, rowptr, col);

    // GAT layers
    hipLaunchKernelGGL(gemm1_kernel, dim3((N + 127) / 128), dim3(512), 0, stream,
                       x, W1, a_s1, a_d1, h1b, as1, ad1, N);
    hipLaunchKernelGGL(agg1_kernel, dim3((N + 3) / 4), dim3(256), 0, stream,
                       rowptr, col, h1b, as1, ad1, b1, out1, N);
    hipLaunchKernelGGL(gemm2_kernel, dim3((N + 63) / 64), dim3(256), 0, stream,
                       out1, W2, a_s2, a_d2, h2b, as2, ad2, N);
    hipLaunchKernelGGL(agg2_kernel, dim3((N + 3) / 4), dim3(256), 0, stream,
                       rowptr, col, h2b, as2, ad2, b2, (float*)d_out, N);
}

// Round 5
// 279.533 us; speedup vs baseline: 2.6762x; 1.0370x over previous
//
#include <hip/hip_runtime.h>
#include <math.h>

#define NEG_SLOPE 0.2f
#define EPB 8192            // edges per P1 block

__device__ __forceinline__ unsigned pack_bf16x2(float a, float b) {
    unsigned ua = __float_as_uint(a);
    unsigned ub = __float_as_uint(b);
    ua += 0x7FFFu + ((ua >> 16) & 1u);     // RNE
    ub += 0x7FFFu + ((ub >> 16) & 1u);
    return (ua >> 16) | (ub & 0xFFFF0000u);
}
__device__ __forceinline__ float bf_lo(unsigned u) { return __uint_as_float(u << 16); }
__device__ __forceinline__ float bf_hi(unsigned u) { return __uint_as_float(u & 0xFFFF0000u); }

// ================= generic in-place exclusive scan (3 kernels) =================

__global__ __launch_bounds__(256) void gscan_bsum(const int* __restrict__ arr,
                                                  int* __restrict__ psum, int M) {
    __shared__ int red[4];
    int tid = threadIdx.x;
    int idx = blockIdx.x * 256 + tid;
    int v = (idx < M) ? arr[idx] : 0;
    #pragma unroll
    for (int off = 1; off < 64; off <<= 1) v += __shfl_xor(v, off, 64);
    if ((tid & 63) == 0) red[tid >> 6] = v;
    __syncthreads();
    if (tid == 0) psum[blockIdx.x] = red[0] + red[1] + red[2] + red[3];
}

__global__ __launch_bounds__(1024) void gscan_psum(int* __restrict__ psum, int nb) {
    __shared__ int ws[16];
    int tid = threadIdx.x, lane = tid & 63, w = tid >> 6;
    int v = (tid < nb) ? psum[tid] : 0;
    int incl = v;
    #pragma unroll
    for (int off = 1; off < 64; off <<= 1) {
        int t = __shfl_up(incl, off, 64);
        if (lane >= off) incl += t;
    }
    if (lane == 63) ws[w] = incl;
    __syncthreads();
    int wbase = 0;
    #pragma unroll
    for (int j = 0; j < 16; j++) { if (j < w) wbase += ws[j]; }
    if (tid < nb) psum[tid] = wbase + incl - v;   // exclusive
}

__global__ __launch_bounds__(256) void gscan_final(int* __restrict__ arr,
                                                   const int* __restrict__ psum, int M) {
    __shared__ int ws[4];
    int tid = threadIdx.x, lane = tid & 63, w = tid >> 6;
    int idx = blockIdx.x * 256 + tid;
    int v = (idx < M) ? arr[idx] : 0;
    int incl = v;
    #pragma unroll
    for (int off = 1; off < 64; off <<= 1) {
        int t = __shfl_up(incl, off, 64);
        if (lane >= off) incl += t;
    }
    if (lane == 63) ws[w] = incl;
    __syncthreads();
    int wbase = 0;
    #pragma unroll
    for (int j = 0; j < 4; j++) { if (j < w) wbase += ws[j]; }
    if (idx < M) arr[idx] = psum[blockIdx.x] + wbase + incl - v;
}

// ================= CSR build: two-level counting sort, LDS atomics only =================
// bucket = dst >> 8; pair packed as (local_dst<<24) | src  (src < 2^24).

__global__ __launch_bounds__(256) void p1_hist(const int* __restrict__ dst, int E, int N,
                                               int nblk1, int nbuckets,
                                               int* __restrict__ partial) {
    __shared__ int hist[1024];
    int tid = threadIdx.x;
    for (int i = tid; i < nbuckets; i += 256) hist[i] = 0;
    __syncthreads();
    int base = blockIdx.x * EPB;
    int tot = E + N;
    #pragma unroll
    for (int it = 0; it < EPB / 256; it++) {
        int i = base + it * 256 + tid;
        if (i < tot) {
            int d = (i < E) ? dst[i] : (i - E);   // self-loops appended
            atomicAdd(&hist[d >> 8], 1);          // LDS atomic
        }
    }
    __syncthreads();
    for (int b = tid; b < nbuckets; b += 256)
        partial[b * nblk1 + blockIdx.x] = hist[b];   // bucket-major
}

__global__ __launch_bounds__(256) void p1_scatter(const int* __restrict__ src,
                                                  const int* __restrict__ dst, int E, int N,
                                                  int nblk1, int nbuckets,
                                                  const int* __restrict__ scanned,
                                                  unsigned* __restrict__ pairs) {
    __shared__ int cursor[1024];
    int tid = threadIdx.x;
    for (int b = tid; b < nbuckets; b += 256)
        cursor[b] = scanned[b * nblk1 + blockIdx.x];
    __syncthreads();
    int base = blockIdx.x * EPB;
    int tot = E + N;
    #pragma unroll
    for (int it = 0; it < EPB / 256; it++) {
        int i = base + it * 256 + tid;
        if (i < tot) {
            int s = (i < E) ? src[i] : (i - E);
            int d = (i < E) ? dst[i] : (i - E);
            int pos = atomicAdd(&cursor[d >> 8], 1);  // LDS atomic w/ return
            pairs[pos] = ((unsigned)(d & 255) << 24) | (unsigned)s;
        }
    }
}

#define P2CAP 8192

__global__ __launch_bounds__(256) void p2_kernel(const unsigned* __restrict__ pairs,
                                                 const int* __restrict__ scanned,
                                                 int nblk1, int nbuckets, int Etot, int N,
                                                 int* __restrict__ rowptr,
                                                 int* __restrict__ col) {
    __shared__ unsigned buf[P2CAP];     // 32 KB: bucket staged once from global
    __shared__ int cnt[256];
    __shared__ int cur[256];
    __shared__ int wsum[4];
    int b = blockIdx.x;
    int tid = threadIdx.x, lane = tid & 63, w = tid >> 6;
    int bucketStart = scanned[b * nblk1];
    int bucketEnd = (b + 1 < nbuckets) ? scanned[(b + 1) * nblk1] : Etot;
    int sz = bucketEnd - bucketStart;
    bool inLds = (sz <= P2CAP);
    cnt[tid] = 0;
    if (inLds) {
        for (int i = tid; i < sz; i += 256) buf[i] = pairs[bucketStart + i];
    }
    __syncthreads();
    if (inLds) {
        for (int i = tid; i < sz; i += 256) atomicAdd(&cnt[buf[i] >> 24], 1);
    } else {
        for (int i = bucketStart + tid; i < bucketEnd; i += 256)
            atomicAdd(&cnt[pairs[i] >> 24], 1);
    }
    __syncthreads();
    int v = cnt[tid];
    int incl = v;
    #pragma unroll
    for (int off = 1; off < 64; off <<= 1) {
        int t = __shfl_up(incl, off, 64);
        if (lane >= off) incl += t;
    }
    if (lane == 63) wsum[w] = incl;
    __syncthreads();
    int wbase = 0;
    #pragma unroll
    for (int j = 0; j < 4; j++) { if (j < w) wbase += wsum[j]; }
    int base = bucketStart + wbase + incl - v;   // exclusive position for this local dst
    cur[tid] = base;
    int d = b * 256 + tid;
    if (d < N) rowptr[d] = base;
    if (b == nbuckets - 1 && tid == 0) rowptr[N] = Etot;
    __syncthreads();
    if (inLds) {
        for (int i = tid; i < sz; i += 256) {
            unsigned p = buf[i];
            int pos = atomicAdd(&cur[p >> 24], 1);
            col[pos] = (int)(p & 0xFFFFFFu);
        }
    } else {
        for (int i = bucketStart + tid; i < bucketEnd; i += 256) {
            unsigned p = pairs[i];
            int pos = atomicAdd(&cur[p >> 24], 1);
            col[pos] = (int)(p & 0xFFFFFFu);
        }
    }
}

// ---------------- Layer 1 GEMM: h1(bf16) = x @ W1, plus as1/ad1 (fp32) ----------------

#define XPAD 132

__global__ __launch_bounds__(512) void gemm1_kernel(const float* __restrict__ x,
                                                    const float* __restrict__ W,
                                                    const float* __restrict__ a_s,
                                                    const float* __restrict__ a_d,
                                                    unsigned* __restrict__ h1b,
                                                    float* __restrict__ as1,
                                                    float* __restrict__ ad1, int N) {
    __shared__ float xs[128 * XPAD];
    __shared__ float Ws[128 * 128];
    __shared__ float red[2 * 128 * 16];
    int tid = threadIdx.x;
    int row0 = blockIdx.x * 128;
    {
        const float4* W4 = (const float4*)W;
        float4* Ws4 = (float4*)Ws;
        #pragma unroll
        for (int it = 0; it < 8; it++) Ws4[tid + it * 512] = W4[tid + it * 512];
    }
    #pragma unroll
    for (int it = 0; it < 8; it++) {
        int i = tid + it * 512;
        int r = i >> 5, k4 = i & 31;
        int row = row0 + r;
        float4 v = (row < N) ? ((const float4*)x)[row * 32 + k4] : make_float4(0.f, 0.f, 0.f, 0.f);
        *(float4*)&xs[r * XPAD + k4 * 4] = v;
    }
    __syncthreads();

    int cc = tid & 15, rr = tid >> 4;
    float acc[4][8];
    #pragma unroll
    for (int r = 0; r < 4; r++)
        #pragma unroll
        for (int j = 0; j < 8; j++) acc[r][j] = 0.f;

    for (int k4 = 0; k4 < 32; k4++) {
        float4 xk[4];
        #pragma unroll
        for (int r = 0; r < 4; r++)
            xk[r] = *(const float4*)&xs[(rr * 4 + r) * XPAD + k4 * 4];
        #pragma unroll
        for (int kk = 0; kk < 4; kk++) {
            int k = k4 * 4 + kk;
            float4 w0 = *(const float4*)&Ws[k * 128 + cc * 8];
            float4 w1 = *(const float4*)&Ws[k * 128 + cc * 8 + 4];
            #pragma unroll
            for (int r = 0; r < 4; r++) {
                float xv = ((const float*)&xk[r])[kk];
                acc[r][0] = fmaf(xv, w0.x, acc[r][0]);
                acc[r][1] = fmaf(xv, w0.y, acc[r][1]);
                acc[r][2] = fmaf(xv, w0.z, acc[r][2]);
                acc[r][3] = fmaf(xv, w0.w, acc[r][3]);
                acc[r][4] = fmaf(xv, w1.x, acc[r][4]);
                acc[r][5] = fmaf(xv, w1.y, acc[r][5]);
                acc[r][6] = fmaf(xv, w1.z, acc[r][6]);
                acc[r][7] = fmaf(xv, w1.w, acc[r][7]);
            }
        }
    }

    #pragma unroll
    for (int r = 0; r < 4; r++) {
        float sd = 0.f, dd = 0.f;
        #pragma unroll
        for (int j = 0; j < 8; j++) {
            sd = fmaf(acc[r][j], a_s[cc * 8 + j], sd);
            dd = fmaf(acc[r][j], a_d[cc * 8 + j], dd);
        }
        red[(rr * 4 + r) * 16 + cc] = sd;
        red[2048 + (rr * 4 + r) * 16 + cc] = dd;
    }
    #pragma unroll
    for (int r = 0; r < 4; r++) {
        int row = row0 + rr * 4 + r;
        if (row < N) {
            uint4 pk;
            pk.x = pack_bf16x2(acc[r][0], acc[r][1]);
            pk.y = pack_bf16x2(acc[r][2], acc[r][3]);
            pk.z = pack_bf16x2(acc[r][4], acc[r][5]);
            pk.w = pack_bf16x2(acc[r][6], acc[r][7]);
            *(uint4*)&h1b[row * 64 + cc * 4] = pk;
        }
    }
    __syncthreads();
    {
        int row = tid >> 2, h = tid & 3;
        if (row0 + row < N) {
            float s = red[row * 16 + h * 4] + red[row * 16 + h * 4 + 1] +
                      red[row * 16 + h * 4 + 2] + red[row * 16 + h * 4 + 3];
            float d = red[2048 + row * 16 + h * 4] + red[2048 + row * 16 + h * 4 + 1] +
                      red[2048 + row * 16 + h * 4 + 2] + red[2048 + row * 16 + h * 4 + 3];
            as1[(row0 + row) * 4 + h] = s;
            ad1[(row0 + row) * 4 + h] = d;
        }
    }
}

// ---------------- Layer 1 aggregation: bf16 gather, unroll x8, bf16 out ----------------

__device__ __forceinline__ float sel4(float4 a, int h) {
    return h < 2 ? (h == 0 ? a.x : a.y) : (h == 2 ? a.z : a.w);
}

#define AGG1_EDGE(u, A)                                            \
    {                                                              \
        float e = sel4(A, hh) + adn;                               \
        e = fmaxf(e, e * NEG_SLOPE);                               \
        float ex = __expf(e);                                      \
        den += ex;                                                 \
        ax = fmaf(ex, bf_lo(u), ax);                               \
        ay = fmaf(ex, bf_hi(u), ay);                               \
    }

__global__ __launch_bounds__(256) void agg1_kernel(const int* __restrict__ rowptr,
                                                   const int* __restrict__ col,
                                                   const unsigned* __restrict__ h1b,
                                                   const float* __restrict__ as1,
                                                   const float* __restrict__ ad1,
                                                   const float* __restrict__ b1,
                                                   unsigned* __restrict__ out1b, int N) {
    int lane = threadIdx.x & 63;
    int wid = __builtin_amdgcn_readfirstlane(threadIdx.x >> 6);
    int n = blockIdx.x * 4 + wid;
    if (n >= N) return;
    int hh = lane >> 4;                  // head of channels 2*lane, 2*lane+1
    const float4* as4 = (const float4*)as1;
    float adn = sel4(((const float4*)ad1)[n], hh);
    int beg = rowptr[n], end = rowptr[n + 1];
    float ax = 0.f, ay = 0.f, den = 0.f;
    int i = beg;
    for (; i + 8 <= end; i += 8) {
        int s0 = col[i],     s1 = col[i + 1], s2 = col[i + 2], s3 = col[i + 3];
        int s4 = col[i + 4], s5 = col[i + 5], s6 = col[i + 6], s7 = col[i + 7];
        unsigned u0 = h1b[s0 * 64 + lane];
        unsigned u1 = h1b[s1 * 64 + lane];
        unsigned u2 = h1b[s2 * 64 + lane];
        unsigned u3 = h1b[s3 * 64 + lane];
        unsigned u4 = h1b[s4 * 64 + lane];
        unsigned u5 = h1b[s5 * 64 + lane];
        unsigned u6 = h1b[s6 * 64 + lane];
        unsigned u7 = h1b[s7 * 64 + lane];
        float4 A0 = as4[s0], A1 = as4[s1], A2 = as4[s2], A3 = as4[s3];
        float4 A4 = as4[s4], A5 = as4[s5], A6 = as4[s6], A7 = as4[s7];
        AGG1_EDGE(u0, A0) AGG1_EDGE(u1, A1) AGG1_EDGE(u2, A2) AGG1_EDGE(u3, A3)
        AGG1_EDGE(u4, A4) AGG1_EDGE(u5, A5) AGG1_EDGE(u6, A6) AGG1_EDGE(u7, A7)
    }
    for (; i + 4 <= end; i += 4) {
        int s0 = col[i], s1 = col[i + 1], s2 = col[i + 2], s3 = col[i + 3];
        unsigned u0 = h1b[s0 * 64 + lane];
        unsigned u1 = h1b[s1 * 64 + lane];
        unsigned u2 = h1b[s2 * 64 + lane];
        unsigned u3 = h1b[s3 * 64 + lane];
        float4 A0 = as4[s0], A1 = as4[s1], A2 = as4[s2], A3 = as4[s3];
        AGG1_EDGE(u0, A0) AGG1_EDGE(u1, A1) AGG1_EDGE(u2, A2) AGG1_EDGE(u3, A3)
    }
    for (; i < end; i++) {
        int s = col[i];
        unsigned u = h1b[s * 64 + lane];
        float4 A = as4[s];
        AGG1_EDGE(u, A)
    }
    float2 bb = ((const float2*)b1)[lane];
    float ox = fmaxf(ax / den + bb.x, 0.f);
    float oy = fmaxf(ay / den + bb.y, 0.f);
    out1b[n * 64 + lane] = pack_bf16x2(ox, oy);
}

// ---------------- Layer 2 GEMM: h2(bf16) = relu_h(bf16) @ W2, plus as2/ad2 ----------------

__global__ __launch_bounds__(256) void gemm2_kernel(const unsigned* __restrict__ out1b,
                                                    const float* __restrict__ W,
                                                    const float* __restrict__ a_s,
                                                    const float* __restrict__ a_d,
                                                    unsigned* __restrict__ h2b,
                                                    float* __restrict__ as2,
                                                    float* __restrict__ ad2, int N) {
    __shared__ float Ws[128 * 32];
    __shared__ float xs[64 * 129];
    __shared__ float red[64 * 8];
    int tid = threadIdx.x;
    {
        const float4* W4 = (const float4*)W;
        float4* Ws4 = (float4*)Ws;
        #pragma unroll
        for (int it = 0; it < 4; it++) Ws4[tid + it * 256] = W4[tid + it * 256];
    }
    int row0 = blockIdx.x * 64;
    #pragma unroll
    for (int it = 0; it < 4; it++) {
        int i = tid + it * 256;           // uint4 granule: 0..1023 (64 rows x 16)
        int r = i >> 4, c8 = i & 15;
        int row = row0 + r;
        uint4 v = (row < N) ? ((const uint4*)out1b)[row * 16 + c8] : make_uint4(0, 0, 0, 0);
        float* dst = &xs[r * 129 + c8 * 8];
        dst[0] = bf_lo(v.x); dst[1] = bf_hi(v.x);
        dst[2] = bf_lo(v.y); dst[3] = bf_hi(v.y);
        dst[4] = bf_lo(v.z); dst[5] = bf_hi(v.z);
        dst[6] = bf_lo(v.w); dst[7] = bf_hi(v.w);
    }
    __syncthreads();

    int r = tid & 63, g = tid >> 6;
    float acc[8];
    #pragma unroll
    for (int j = 0; j < 8; j++) acc[j] = 0.f;
    for (int k = 0; k < 128; k++) {
        float xv = xs[r * 129 + k];
        const float* w = &Ws[k * 32 + g * 8];
        #pragma unroll
        for (int j = 0; j < 8; j++) acc[j] = fmaf(xv, w[j], acc[j]);
    }

    float sd = 0.f, dd = 0.f;
    #pragma unroll
    for (int j = 0; j < 8; j++) {
        sd = fmaf(acc[j], a_s[g * 8 + j], sd);
        dd = fmaf(acc[j], a_d[g * 8 + j], dd);
    }
    red[r * 8 + g] = sd;
    red[r * 8 + 4 + g] = dd;
    int row = row0 + r;
    if (row < N) {
        uint4 pk;
        pk.x = pack_bf16x2(acc[0], acc[1]);
        pk.y = pack_bf16x2(acc[2], acc[3]);
        pk.z = pack_bf16x2(acc[4], acc[5]);
        pk.w = pack_bf16x2(acc[6], acc[7]);
        *(uint4*)&h2b[row * 16 + g * 4] = pk;
    }
    __syncthreads();
    if (tid < 64 && row0 + tid < N) {
        as2[row0 + tid] = red[tid * 8 + 0] + red[tid * 8 + 1] + red[tid * 8 + 2] + red[tid * 8 + 3];
        ad2[row0 + tid] = red[tid * 8 + 4] + red[tid * 8 + 5] + red[tid * 8 + 6] + red[tid * 8 + 7];
    }
}

// ---------------- Layer 2 aggregation: 16 edges/wave in flight ----------------

#define AGG2_EDGE(u, l)                                            \
    {                                                              \
        float e = l + adn;                                         \
        e = fmaxf(e, e * NEG_SLOPE);                               \
        float ex = __expf(e);                                      \
        den += ex;                                                 \
        a0 = fmaf(ex, bf_lo(u), a0);                               \
        a1 = fmaf(ex, bf_hi(u), a1);                               \
    }

__global__ __launch_bounds__(256) void agg2_kernel(const int* __restrict__ rowptr,
                                                   const int* __restrict__ col,
                                                   const unsigned* __restrict__ h2b,
                                                   const float* __restrict__ as2,
                                                   const float* __restrict__ ad2,
                                                   const float* __restrict__ b2,
                                                   float* __restrict__ out, int N) {
    int lane = threadIdx.x & 63;
    int wid = __builtin_amdgcn_readfirstlane(threadIdx.x >> 6);
    int n = blockIdx.x * 4 + wid;
    if (n >= N) return;
    int q = lane >> 4, c2 = lane & 15;
    float adn = ad2[n];
    int beg = rowptr[n], end = rowptr[n + 1];
    float a0 = 0.f, a1 = 0.f, den = 0.f;
    int i = beg;
    for (; i + 16 <= end; i += 16) {
        int s0 = col[i + q];
        int s1 = col[i + 4 + q];
        int s2 = col[i + 8 + q];
        int s3 = col[i + 12 + q];
        unsigned u0 = h2b[s0 * 16 + c2];
        unsigned u1 = h2b[s1 * 16 + c2];
        unsigned u2 = h2b[s2 * 16 + c2];
        unsigned u3 = h2b[s3 * 16 + c2];
        float l0 = as2[s0], l1 = as2[s1], l2 = as2[s2], l3 = as2[s3];
        AGG2_EDGE(u0, l0) AGG2_EDGE(u1, l1) AGG2_EDGE(u2, l2) AGG2_EDGE(u3, l3)
    }
    for (; i + 4 <= end; i += 4) {
        int s = col[i + q];
        unsigned u = h2b[s * 16 + c2];
        float l = as2[s];
        AGG2_EDGE(u, l)
    }
    if (i + q < end) {
        int s = col[i + q];
        unsigned u = h2b[s * 16 + c2];
        float l = as2[s];
        AGG2_EDGE(u, l)
    }
    den += __shfl_xor(den, 16, 64);
    den += __shfl_xor(den, 32, 64);
    a0 += __shfl_xor(a0, 16, 64);
    a0 += __shfl_xor(a0, 32, 64);
    a1 += __shfl_xor(a1, 16, 64);
    a1 += __shfl_xor(a1, 32, 64);
    if (q == 0) {
        float2 bb = ((const float2*)b2)[c2];
        ((float2*)out)[n * 16 + c2] = make_float2(a0 / den + bb.x, a1 / den + bb.y);
    }
}

// ---------------- launch ----------------

extern "C" void kernel_launch(void* const* d_in, const int* in_sizes, int n_in,
                              void* d_out, int out_size, void* d_ws, size_t ws_size,
                              hipStream_t stream) {
    const float* x    = (const float*)d_in[0];
    const int*   ei   = (const int*)d_in[1];
    const float* W1   = (const float*)d_in[2];
    const float* a_s1 = (const float*)d_in[3];
    const float* a_d1 = (const float*)d_in[4];
    const float* b1   = (const float*)d_in[5];
    const float* W2   = (const float*)d_in[6];
    const float* a_s2 = (const float*)d_in[7];
    const float* a_d2 = (const float*)d_in[8];
    const float* b2   = (const float*)d_in[9];

    int N = in_sizes[0] / 128;
    int E = in_sizes[1] / 2;
    const int* srcA = ei;
    const int* dstA = ei + E;
    int Etot = E + N;

    char* ws = (char*)d_ws;
    size_t off = 0;
    auto alloc = [&](size_t bytes) {
        void* p = ws + off;
        off += (bytes + 255) & ~(size_t)255;
        return p;
    };
    unsigned* h1b   = (unsigned*)alloc((size_t)N * 128 * 2);
    unsigned* out1b = (unsigned*)alloc((size_t)N * 128 * 2);
    unsigned* h2b   = (unsigned*)alloc((size_t)N * 32 * 2);
    float* as1      = (float*)alloc((size_t)N * 4 * 4);
    float* ad1      = (float*)alloc((size_t)N * 4 * 4);
    float* as2      = (float*)alloc((size_t)N * 4);
    float* ad2      = (float*)alloc((size_t)N * 4);
    int*   rowptr   = (int*)alloc((size_t)(N + 1) * 4);
    int*   col      = (int*)alloc((size_t)Etot * 4);
    unsigned* pairs = (unsigned*)alloc((size_t)Etot * 4);

    int nbuckets = (N + 255) >> 8;                 // 391
    int nblk1 = (Etot + EPB - 1) / EPB;            // 208
    int M = nbuckets * nblk1;
    int*   partial = (int*)alloc((size_t)M * 4);
    int nbs = (M + 255) / 256;
    int*   psum    = (int*)alloc((size_t)1024 * 4);

    // CSR build (LDS-atomic two-level counting sort)
    hipLaunchKernelGGL(p1_hist, dim3(nblk1), dim3(256), 0, stream,
                       dstA, E, N, nblk1, nbuckets, partial);
    hipLaunchKernelGGL(gscan_bsum, dim3(nbs), dim3(256), 0, stream, partial, psum, M);
    hipLaunchKernelGGL(gscan_psum, dim3(1), dim3(1024), 0, stream, psum, nbs);
    hipLaunchKernelGGL(gscan_final, dim3(nbs), dim3(256), 0, stream, partial, psum, M);
    hipLaunchKernelGGL(p1_scatter, dim3(nblk1), dim3(256), 0, stream,
                       srcA, dstA, E, N, nblk1, nbuckets, partial, pairs);
    hipLaunchKernelGGL(p2_kernel, dim3(nbuckets), dim3(256), 0, stream,
                       pairs, partial, nblk1, nbuckets, Etot, N, rowptr, col);

    // GAT layers
    hipLaunchKernelGGL(gemm1_kernel, dim3((N + 127) / 128), dim3(512), 0, stream,
                       x, W1, a_s1, a_d1, h1b, as1, ad1, N);
    hipLaunchKernelGGL(agg1_kernel, dim3((N + 3) / 4), dim3(256), 0, stream,
                       rowptr, col, h1b, as1, ad1, b1, out1b, N);
    hipLaunchKernelGGL(gemm2_kernel, dim3((N + 63) / 64), dim3(256), 0, stream,
                       out1b, W2, a_s2, a_d2, h2b, as2, ad2, N);
    hipLaunchKernelGGL(agg2_kernel, dim3((N + 3) / 4), dim3(256), 0, stream,
                       rowptr, col, h2b, as2, ad2, b2, (float*)d_out, N);
}

// Round 6
// 217.711 us; speedup vs baseline: 3.4362x; 1.2840x over previous
//
#include <hip/hip_runtime.h>
#include <math.h>

#define NEG_SLOPE 0.2f
#define EPB 8192            // edges per P1 block

typedef __attribute__((ext_vector_type(8))) short bf16x8;
typedef __attribute__((ext_vector_type(4))) float f32x4;

__device__ __forceinline__ unsigned pack_bf16x2(float a, float b) {
    unsigned ua = __float_as_uint(a);
    unsigned ub = __float_as_uint(b);
    ua += 0x7FFFu + ((ua >> 16) & 1u);     // RNE
    ub += 0x7FFFu + ((ub >> 16) & 1u);
    return (ua >> 16) | (ub & 0xFFFF0000u);
}
__device__ __forceinline__ unsigned short bf16r(float f) {
    unsigned u = __float_as_uint(f);
    u += 0x7FFFu + ((u >> 16) & 1u);
    return (unsigned short)(u >> 16);
}
__device__ __forceinline__ float bf_lo(unsigned u) { return __uint_as_float(u << 16); }
__device__ __forceinline__ float bf_hi(unsigned u) { return __uint_as_float(u & 0xFFFF0000u); }

// LDS tile addressing: row stride 256B, XOR swizzle spreads 16 rows over 16B slots
#define SWZ(row, byteoff) ((((row) * 256) + (byteoff)) ^ (((row) & 15) << 4))

// ================= W transpose+bf16 pre-pass: W[k][Nc] f32 -> WT[n][128] bf16 ===========

__global__ __launch_bounds__(256) void wcvt_kernel(const float* __restrict__ W,
                                                   unsigned short* __restrict__ WT,
                                                   int Nc, int total) {
    int id = blockIdx.x * 256 + threadIdx.x;
    if (id < total) {
        int n = id >> 7, k = id & 127;
        WT[id] = bf16r(W[k * Nc + n]);
    }
}

// ================= generic in-place exclusive scan (3 kernels) =================

__global__ __launch_bounds__(256) void gscan_bsum(const int* __restrict__ arr,
                                                  int* __restrict__ psum, int M) {
    __shared__ int red[4];
    int tid = threadIdx.x;
    int idx = blockIdx.x * 256 + tid;
    int v = (idx < M) ? arr[idx] : 0;
    #pragma unroll
    for (int off = 1; off < 64; off <<= 1) v += __shfl_xor(v, off, 64);
    if ((tid & 63) == 0) red[tid >> 6] = v;
    __syncthreads();
    if (tid == 0) psum[blockIdx.x] = red[0] + red[1] + red[2] + red[3];
}

__global__ __launch_bounds__(1024) void gscan_psum(int* __restrict__ psum, int nb) {
    __shared__ int ws[16];
    int tid = threadIdx.x, lane = tid & 63, w = tid >> 6;
    int v = (tid < nb) ? psum[tid] : 0;
    int incl = v;
    #pragma unroll
    for (int off = 1; off < 64; off <<= 1) {
        int t = __shfl_up(incl, off, 64);
        if (lane >= off) incl += t;
    }
    if (lane == 63) ws[w] = incl;
    __syncthreads();
    int wbase = 0;
    #pragma unroll
    for (int j = 0; j < 16; j++) { if (j < w) wbase += ws[j]; }
    if (tid < nb) psum[tid] = wbase + incl - v;   // exclusive
}

__global__ __launch_bounds__(256) void gscan_final(int* __restrict__ arr,
                                                   const int* __restrict__ psum, int M) {
    __shared__ int ws[4];
    int tid = threadIdx.x, lane = tid & 63, w = tid >> 6;
    int idx = blockIdx.x * 256 + tid;
    int v = (idx < M) ? arr[idx] : 0;
    int incl = v;
    #pragma unroll
    for (int off = 1; off < 64; off <<= 1) {
        int t = __shfl_up(incl, off, 64);
        if (lane >= off) incl += t;
    }
    if (lane == 63) ws[w] = incl;
    __syncthreads();
    int wbase = 0;
    #pragma unroll
    for (int j = 0; j < 4; j++) { if (j < w) wbase += ws[j]; }
    if (idx < M) arr[idx] = psum[blockIdx.x] + wbase + incl - v;
}

// ================= CSR build: two-level counting sort, LDS atomics only =================

__global__ __launch_bounds__(256) void p1_hist(const int* __restrict__ dst, int E, int N,
                                               int nblk1, int nbuckets,
                                               int* __restrict__ partial) {
    __shared__ int hist[1024];
    int tid = threadIdx.x;
    for (int i = tid; i < nbuckets; i += 256) hist[i] = 0;
    __syncthreads();
    int base = blockIdx.x * EPB;
    int tot = E + N;
    #pragma unroll
    for (int it = 0; it < EPB / 256; it++) {
        int i = base + it * 256 + tid;
        if (i < tot) {
            int d = (i < E) ? dst[i] : (i - E);   // self-loops appended
            atomicAdd(&hist[d >> 8], 1);          // LDS atomic
        }
    }
    __syncthreads();
    for (int b = tid; b < nbuckets; b += 256)
        partial[b * nblk1 + blockIdx.x] = hist[b];   // bucket-major
}

__global__ __launch_bounds__(256) void p1_scatter(const int* __restrict__ src,
                                                  const int* __restrict__ dst, int E, int N,
                                                  int nblk1, int nbuckets,
                                                  const int* __restrict__ scanned,
                                                  unsigned* __restrict__ pairs) {
    __shared__ int cursor[1024];
    int tid = threadIdx.x;
    for (int b = tid; b < nbuckets; b += 256)
        cursor[b] = scanned[b * nblk1 + blockIdx.x];
    __syncthreads();
    int base = blockIdx.x * EPB;
    int tot = E + N;
    #pragma unroll
    for (int it = 0; it < EPB / 256; it++) {
        int i = base + it * 256 + tid;
        if (i < tot) {
            int s = (i < E) ? src[i] : (i - E);
            int d = (i < E) ? dst[i] : (i - E);
            int pos = atomicAdd(&cursor[d >> 8], 1);  // LDS atomic w/ return
            pairs[pos] = ((unsigned)(d & 255) << 24) | (unsigned)s;
        }
    }
}

#define P2CAP 8192

__global__ __launch_bounds__(256) void p2_kernel(const unsigned* __restrict__ pairs,
                                                 const int* __restrict__ scanned,
                                                 int nblk1, int nbuckets, int Etot, int N,
                                                 int* __restrict__ rowptr,
                                                 int* __restrict__ col) {
    __shared__ unsigned buf[P2CAP];     // 32 KB: bucket staged once from global
    __shared__ int cnt[256];
    __shared__ int cur[256];
    __shared__ int wsum[4];
    int b = blockIdx.x;
    int tid = threadIdx.x, lane = tid & 63, w = tid >> 6;
    int bucketStart = scanned[b * nblk1];
    int bucketEnd = (b + 1 < nbuckets) ? scanned[(b + 1) * nblk1] : Etot;
    int sz = bucketEnd - bucketStart;
    bool inLds = (sz <= P2CAP);
    cnt[tid] = 0;
    if (inLds) {
        for (int i = tid; i < sz; i += 256) buf[i] = pairs[bucketStart + i];
    }
    __syncthreads();
    if (inLds) {
        for (int i = tid; i < sz; i += 256) atomicAdd(&cnt[buf[i] >> 24], 1);
    } else {
        for (int i = bucketStart + tid; i < bucketEnd; i += 256)
            atomicAdd(&cnt[pairs[i] >> 24], 1);
    }
    __syncthreads();
    int v = cnt[tid];
    int incl = v;
    #pragma unroll
    for (int off = 1; off < 64; off <<= 1) {
        int t = __shfl_up(incl, off, 64);
        if (lane >= off) incl += t;
    }
    if (lane == 63) wsum[w] = incl;
    __syncthreads();
    int wbase = 0;
    #pragma unroll
    for (int j = 0; j < 4; j++) { if (j < w) wbase += wsum[j]; }
    int base = bucketStart + wbase + incl - v;   // exclusive position for this local dst
    cur[tid] = base;
    int d = b * 256 + tid;
    if (d < N) rowptr[d] = base;
    if (b == nbuckets - 1 && tid == 0) rowptr[N] = Etot;
    __syncthreads();
    if (inLds) {
        for (int i = tid; i < sz; i += 256) {
            unsigned p = buf[i];
            int pos = atomicAdd(&cur[p >> 24], 1);
            col[pos] = (int)(p & 0xFFFFFFu);
        }
    } else {
        for (int i = bucketStart + tid; i < bucketEnd; i += 256) {
            unsigned p = pairs[i];
            int pos = atomicAdd(&cur[p >> 24], 1);
            col[pos] = (int)(p & 0xFFFFFFu);
        }
    }
}

// ================= Layer 1 GEMM (MFMA bf16): h1 = x @ W1, plus as1/ad1 =================
// Block: 64 rows, 256 thr (4 waves, 16 rows each). K=128, N=128 (8 n-tiles).
// LDS: xs 64x128 bf16 (16K, swizzled; reused for output tile), ws 128x128 bf16 W1T (32K).

__global__ __launch_bounds__(256) void gemm1_kernel(const float* __restrict__ x,
                                                    const unsigned short* __restrict__ W1T,
                                                    const float* __restrict__ a_s,
                                                    const float* __restrict__ a_d,
                                                    uint4* __restrict__ h1b,
                                                    float* __restrict__ as1,
                                                    float* __restrict__ ad1, int N) {
    __shared__ char xs[16384];          // A tile / later h1 tile (bf16, swizzled)
    __shared__ char wsm[32768];         // B tile = W1T (bf16, swizzled)
    int tid = threadIdx.x;
    int row0 = blockIdx.x * 64;

    // stage W1T [n][k] bf16: 2048 16B granules
    #pragma unroll
    for (int it = 0; it < 8; it++) {
        int idx = it * 256 + tid;
        int n = idx >> 4, kq = idx & 15;
        uint4 v = ((const uint4*)W1T)[idx];
        *(uint4*)(wsm + SWZ(n, kq * 16)) = v;
    }
    // stage x -> bf16: 64 rows x 32 float4
    #pragma unroll
    for (int it = 0; it < 8; it++) {
        int idx = it * 256 + tid;
        int r = idx >> 5, k4 = idx & 31;
        int row = row0 + r;
        float4 v = (row < N) ? ((const float4*)x)[(size_t)row * 32 + k4]
                             : make_float4(0.f, 0.f, 0.f, 0.f);
        uint2 p;
        p.x = pack_bf16x2(v.x, v.y);
        p.y = pack_bf16x2(v.z, v.w);
        *(uint2*)(xs + SWZ(r, k4 * 8)) = p;
    }
    __syncthreads();

    int wv = tid >> 6, lane = tid & 63;
    int r0 = wv * 16;
    int lm = lane & 15, lk = lane >> 4;

    // A fragments: row = r0+lm, k = ks*32 + lk*8 + e
    bf16x8 afr[4];
    #pragma unroll
    for (int ks = 0; ks < 4; ks++) {
        int row = r0 + lm;
        afr[ks] = *(const bf16x8*)(xs + SWZ(row, ks * 64 + lk * 16));
    }
    f32x4 acc[8];
    #pragma unroll
    for (int nt = 0; nt < 8; nt++) acc[nt] = (f32x4){0.f, 0.f, 0.f, 0.f};

    #pragma unroll
    for (int nt = 0; nt < 8; nt++) {
        int c = nt * 16 + lm;
        #pragma unroll
        for (int ks = 0; ks < 4; ks++) {
            bf16x8 bfr = *(const bf16x8*)(wsm + SWZ(c, ks * 64 + lk * 16));
            acc[nt] = __builtin_amdgcn_mfma_f32_16x16x32_bf16(afr[ks], bfr, acc[nt], 0, 0, 0);
        }
    }
    __syncthreads();   // all waves done reading xs -> reuse as output tile

    // scatter acc -> xs as bf16: D[row=r0+lk*4+e][col=nt*16+lm]
    #pragma unroll
    for (int nt = 0; nt < 8; nt++) {
        int c = nt * 16 + lm;
        #pragma unroll
        for (int e = 0; e < 4; e++) {
            int row = r0 + lk * 4 + e;
            *(unsigned short*)(xs + SWZ(row, c * 2)) = bf16r(acc[nt][e]);
        }
    }
    __syncthreads();

    // coalesced h1b write: 64 rows x 16 uint4
    #pragma unroll
    for (int it = 0; it < 4; it++) {
        int idx = it * 256 + tid;
        int row = idx >> 4, q = idx & 15;
        if (row0 + row < N) {
            uint4 v = *(const uint4*)(xs + SWZ(row, q * 16));
            h1b[(size_t)(row0 + row) * 16 + q] = v;
        }
    }
    // as1/ad1: thread (row=tid>>2, h=tid&3) dots 32 cols of its head
    {
        int row = tid >> 2, h = tid & 3;
        if (row0 + row < N) {
            float sd = 0.f, dd = 0.f;
            #pragma unroll
            for (int q = 0; q < 4; q++) {
                uint4 v = *(const uint4*)(xs + SWZ(row, h * 64 + q * 16));
                unsigned uu[4] = {v.x, v.y, v.z, v.w};
                #pragma unroll
                for (int j = 0; j < 4; j++) {
                    int k = h * 32 + q * 8 + 2 * j;
                    sd = fmaf(bf_lo(uu[j]), a_s[k], sd);
                    sd = fmaf(bf_hi(uu[j]), a_s[k + 1], sd);
                    dd = fmaf(bf_lo(uu[j]), a_d[k], dd);
                    dd = fmaf(bf_hi(uu[j]), a_d[k + 1], dd);
                }
            }
            as1[(row0 + row) * 4 + h] = sd;
            ad1[(row0 + row) * 4 + h] = dd;
        }
    }
}

// ---------------- Layer 1 aggregation: bf16 gather, 16 edges in flight ----------------

__global__ __launch_bounds__(256) void agg1_kernel(const int* __restrict__ rowptr,
                                                   const int* __restrict__ col,
                                                   const unsigned* __restrict__ h1b,
                                                   const float* __restrict__ as1,
                                                   const float* __restrict__ ad1,
                                                   const float* __restrict__ b1,
                                                   unsigned* __restrict__ out1b, int N) {
    int lane = threadIdx.x & 63;
    int wid = __builtin_amdgcn_readfirstlane(threadIdx.x >> 6);
    int n = blockIdx.x * 4 + wid;
    if (n >= N) return;
    int hh = lane >> 4;                  // head of channels 2*lane, 2*lane+1
    float adn = ad1[n * 4 + hh];
    int beg = rowptr[n], end = rowptr[n + 1];
    float ax0 = 0.f, ay0 = 0.f, den0 = 0.f;
    float ax1 = 0.f, ay1 = 0.f, den1 = 0.f;
    int i = beg;
    for (; i + 16 <= end; i += 16) {
        int ss[16];
        float ll[16];
        unsigned uu[16];
        #pragma unroll
        for (int j = 0; j < 16; j++) ss[j] = col[i + j];
        #pragma unroll
        for (int j = 0; j < 16; j++) {
            ll[j] = as1[ss[j] * 4 + hh];
            uu[j] = h1b[ss[j] * 64 + lane];
        }
        #pragma unroll
        for (int j = 0; j < 16; j++) {
            float e = ll[j] + adn;
            e = fmaxf(e, e * NEG_SLOPE);
            float ex = __expf(e);
            if (j & 1) {
                den1 += ex;
                ax1 = fmaf(ex, bf_lo(uu[j]), ax1);
                ay1 = fmaf(ex, bf_hi(uu[j]), ay1);
            } else {
                den0 += ex;
                ax0 = fmaf(ex, bf_lo(uu[j]), ax0);
                ay0 = fmaf(ex, bf_hi(uu[j]), ay0);
            }
        }
    }
    for (; i + 4 <= end; i += 4) {
        int ss[4];
        float ll[4];
        unsigned uu[4];
        #pragma unroll
        for (int j = 0; j < 4; j++) ss[j] = col[i + j];
        #pragma unroll
        for (int j = 0; j < 4; j++) {
            ll[j] = as1[ss[j] * 4 + hh];
            uu[j] = h1b[ss[j] * 64 + lane];
        }
        #pragma unroll
        for (int j = 0; j < 4; j++) {
            float e = ll[j] + adn;
            e = fmaxf(e, e * NEG_SLOPE);
            float ex = __expf(e);
            den0 += ex;
            ax0 = fmaf(ex, bf_lo(uu[j]), ax0);
            ay0 = fmaf(ex, bf_hi(uu[j]), ay0);
        }
    }
    for (; i < end; i++) {
        int s = col[i];
        float l = as1[s * 4 + hh];
        unsigned u = h1b[s * 64 + lane];
        float e = l + adn;
        e = fmaxf(e, e * NEG_SLOPE);
        float ex = __expf(e);
        den0 += ex;
        ax0 = fmaf(ex, bf_lo(u), ax0);
        ay0 = fmaf(ex, bf_hi(u), ay0);
    }
    float den = den0 + den1, ax = ax0 + ax1, ay = ay0 + ay1;
    float2 bb = ((const float2*)b1)[lane];
    float ox = fmaxf(ax / den + bb.x, 0.f);
    float oy = fmaxf(ay / den + bb.y, 0.f);
    out1b[n * 64 + lane] = pack_bf16x2(ox, oy);
}

// ================= Layer 2 GEMM (MFMA bf16): h2 = relu_h @ W2, plus as2/ad2 =============
// Block: 64 rows, 256 thr. K=128, N=32 (2 n-tiles). Input already bf16.

__global__ __launch_bounds__(256) void gemm2_kernel(const uint4* __restrict__ out1b,
                                                    const unsigned short* __restrict__ W2T,
                                                    const float* __restrict__ a_s,
                                                    const float* __restrict__ a_d,
                                                    uint4* __restrict__ h2b,
                                                    float* __restrict__ as2,
                                                    float* __restrict__ ad2, int N) {
    __shared__ char xs[16384];          // A tile / later h2 tile
    __shared__ char wsm[8192];          // W2T 32x128 bf16
    int tid = threadIdx.x;
    int row0 = blockIdx.x * 64;

    // stage W2T: 512 granules
    #pragma unroll
    for (int it = 0; it < 2; it++) {
        int idx = it * 256 + tid;
        int n = idx >> 4, kq = idx & 15;
        uint4 v = ((const uint4*)W2T)[idx];
        *(uint4*)(wsm + SWZ(n, kq * 16)) = v;
    }
    // stage input rows (bf16 already): 64 rows x 16 granules
    #pragma unroll
    for (int it = 0; it < 4; it++) {
        int idx = it * 256 + tid;
        int r = idx >> 4, q = idx & 15;
        int row = row0 + r;
        uint4 v = (row < N) ? out1b[(size_t)row * 16 + q] : make_uint4(0, 0, 0, 0);
        *(uint4*)(xs + SWZ(r, q * 16)) = v;
    }
    __syncthreads();

    int wv = tid >> 6, lane = tid & 63;
    int r0 = wv * 16;
    int lm = lane & 15, lk = lane >> 4;

    bf16x8 afr[4];
    #pragma unroll
    for (int ks = 0; ks < 4; ks++) {
        int row = r0 + lm;
        afr[ks] = *(const bf16x8*)(xs + SWZ(row, ks * 64 + lk * 16));
    }
    f32x4 acc[2];
    acc[0] = (f32x4){0.f, 0.f, 0.f, 0.f};
    acc[1] = (f32x4){0.f, 0.f, 0.f, 0.f};
    #pragma unroll
    for (int nt = 0; nt < 2; nt++) {
        int c = nt * 16 + lm;
        #pragma unroll
        for (int ks = 0; ks < 4; ks++) {
            bf16x8 bfr = *(const bf16x8*)(wsm + SWZ(c, ks * 64 + lk * 16));
            acc[nt] = __builtin_amdgcn_mfma_f32_16x16x32_bf16(afr[ks], bfr, acc[nt], 0, 0, 0);
        }
    }
    __syncthreads();

    #pragma unroll
    for (int nt = 0; nt < 2; nt++) {
        int c = nt * 16 + lm;
        #pragma unroll
        for (int e = 0; e < 4; e++) {
            int row = r0 + lk * 4 + e;
            *(unsigned short*)(xs + SWZ(row, c * 2)) = bf16r(acc[nt][e]);
        }
    }
    __syncthreads();

    // h2b write: 64 rows x 4 uint4
    {
        int row = tid >> 2, q = tid & 3;
        if (row0 + row < N) {
            uint4 v = *(const uint4*)(xs + SWZ(row, q * 16));
            h2b[(size_t)(row0 + row) * 4 + q] = v;
        }
    }
    // as2/ad2: one thread per row
    if (tid < 64 && row0 + tid < N) {
        float sd = 0.f, dd = 0.f;
        #pragma unroll
        for (int q = 0; q < 4; q++) {
            uint4 v = *(const uint4*)(xs + SWZ(tid, q * 16));
            unsigned uu[4] = {v.x, v.y, v.z, v.w};
            #pragma unroll
            for (int j = 0; j < 4; j++) {
                int k = q * 8 + 2 * j;
                sd = fmaf(bf_lo(uu[j]), a_s[k], sd);
                sd = fmaf(bf_hi(uu[j]), a_s[k + 1], sd);
                dd = fmaf(bf_lo(uu[j]), a_d[k], dd);
                dd = fmaf(bf_hi(uu[j]), a_d[k + 1], dd);
            }
        }
        as2[row0 + tid] = sd;
        ad2[row0 + tid] = dd;
    }
}

// ---------------- Layer 2 aggregation: 16 edges/wave in flight ----------------

#define AGG2_EDGE(u, l)                                            \
    {                                                              \
        float e = l + adn;                                         \
        e = fmaxf(e, e * NEG_SLOPE);                               \
        float ex = __expf(e);                                      \
        den += ex;                                                 \
        a0 = fmaf(ex, bf_lo(u), a0);                               \
        a1 = fmaf(ex, bf_hi(u), a1);                               \
    }

__global__ __launch_bounds__(256) void agg2_kernel(const int* __restrict__ rowptr,
                                                   const int* __restrict__ col,
                                                   const unsigned* __restrict__ h2b,
                                                   const float* __restrict__ as2,
                                                   const float* __restrict__ ad2,
                                                   const float* __restrict__ b2,
                                                   float* __restrict__ out, int N) {
    int lane = threadIdx.x & 63;
    int wid = __builtin_amdgcn_readfirstlane(threadIdx.x >> 6);
    int n = blockIdx.x * 4 + wid;
    if (n >= N) return;
    int q = lane >> 4, c2 = lane & 15;
    float adn = ad2[n];
    int beg = rowptr[n], end = rowptr[n + 1];
    float a0 = 0.f, a1 = 0.f, den = 0.f;
    int i = beg;
    for (; i + 16 <= end; i += 16) {
        int s0 = col[i + q];
        int s1 = col[i + 4 + q];
        int s2 = col[i + 8 + q];
        int s3 = col[i + 12 + q];
        unsigned u0 = h2b[s0 * 16 + c2];
        unsigned u1 = h2b[s1 * 16 + c2];
        unsigned u2 = h2b[s2 * 16 + c2];
        unsigned u3 = h2b[s3 * 16 + c2];
        float l0 = as2[s0], l1 = as2[s1], l2 = as2[s2], l3 = as2[s3];
        AGG2_EDGE(u0, l0) AGG2_EDGE(u1, l1) AGG2_EDGE(u2, l2) AGG2_EDGE(u3, l3)
    }
    for (; i + 4 <= end; i += 4) {
        int s = col[i + q];
        unsigned u = h2b[s * 16 + c2];
        float l = as2[s];
        AGG2_EDGE(u, l)
    }
    if (i + q < end) {
        int s = col[i + q];
        unsigned u = h2b[s * 16 + c2];
        float l = as2[s];
        AGG2_EDGE(u, l)
    }
    den += __shfl_xor(den, 16, 64);
    den += __shfl_xor(den, 32, 64);
    a0 += __shfl_xor(a0, 16, 64);
    a0 += __shfl_xor(a0, 32, 64);
    a1 += __shfl_xor(a1, 16, 64);
    a1 += __shfl_xor(a1, 32, 64);
    if (q == 0) {
        float2 bb = ((const float2*)b2)[c2];
        ((float2*)out)[n * 16 + c2] = make_float2(a0 / den + bb.x, a1 / den + bb.y);
    }
}

// ---------------- launch ----------------

extern "C" void kernel_launch(void* const* d_in, const int* in_sizes, int n_in,
                              void* d_out, int out_size, void* d_ws, size_t ws_size,
                              hipStream_t stream) {
    const float* x    = (const float*)d_in[0];
    const int*   ei   = (const int*)d_in[1];
    const float* W1   = (const float*)d_in[2];
    const float* a_s1 = (const float*)d_in[3];
    const float* a_d1 = (const float*)d_in[4];
    const float* b1   = (const float*)d_in[5];
    const float* W2   = (const float*)d_in[6];
    const float* a_s2 = (const float*)d_in[7];
    const float* a_d2 = (const float*)d_in[8];
    const float* b2   = (const float*)d_in[9];

    int N = in_sizes[0] / 128;
    int E = in_sizes[1] / 2;
    const int* srcA = ei;
    const int* dstA = ei + E;
    int Etot = E + N;

    char* ws = (char*)d_ws;
    size_t off = 0;
    auto alloc = [&](size_t bytes) {
        void* p = ws + off;
        off += (bytes + 255) & ~(size_t)255;
        return p;
    };
    unsigned* h1b   = (unsigned*)alloc((size_t)N * 128 * 2);
    unsigned* out1b = (unsigned*)alloc((size_t)N * 128 * 2);
    unsigned* h2b   = (unsigned*)alloc((size_t)N * 32 * 2);
    float* as1      = (float*)alloc((size_t)N * 4 * 4);
    float* ad1      = (float*)alloc((size_t)N * 4 * 4);
    float* as2      = (float*)alloc((size_t)N * 4);
    float* ad2      = (float*)alloc((size_t)N * 4);
    int*   rowptr   = (int*)alloc((size_t)(N + 1) * 4);
    int*   col      = (int*)alloc((size_t)Etot * 4);
    unsigned* pairs = (unsigned*)alloc((size_t)Etot * 4);
    unsigned short* W1T = (unsigned short*)alloc(128 * 128 * 2);
    unsigned short* W2T = (unsigned short*)alloc(32 * 128 * 2);

    int nbuckets = (N + 255) >> 8;                 // 391
    int nblk1 = (Etot + EPB - 1) / EPB;            // 208
    int M = nbuckets * nblk1;
    int*   partial = (int*)alloc((size_t)M * 4);
    int nbs = (M + 255) / 256;
    int*   psum    = (int*)alloc((size_t)1024 * 4);

    // weight transpose/convert
    hipLaunchKernelGGL(wcvt_kernel, dim3(64), dim3(256), 0, stream, W1, W1T, 128, 16384);
    hipLaunchKernelGGL(wcvt_kernel, dim3(16), dim3(256), 0, stream, W2, W2T, 32, 4096);

    // CSR build (LDS-atomic two-level counting sort)
    hipLaunchKernelGGL(p1_hist, dim3(nblk1), dim3(256), 0, stream,
                       dstA, E, N, nblk1, nbuckets, partial);
    hipLaunchKernelGGL(gscan_bsum, dim3(nbs), dim3(256), 0, stream, partial, psum, M);
    hipLaunchKernelGGL(gscan_psum, dim3(1), dim3(1024), 0, stream, psum, nbs);
    hipLaunchKernelGGL(gscan_final, dim3(nbs), dim3(256), 0, stream, partial, psum, M);
    hipLaunchKernelGGL(p1_scatter, dim3(nblk1), dim3(256), 0, stream,
                       srcA, dstA, E, N, nblk1, nbuckets, partial, pairs);
    hipLaunchKernelGGL(p2_kernel, dim3(nbuckets), dim3(256), 0, stream,
                       pairs, partial, nblk1, nbuckets, Etot, N, rowptr, col);

    // GAT layers
    hipLaunchKernelGGL(gemm1_kernel, dim3((N + 63) / 64), dim3(256), 0, stream,
                       x, W1T, a_s1, a_d1, (uint4*)h1b, as1, ad1, N);
    hipLaunchKernelGGL(agg1_kernel, dim3((N + 3) / 4), dim3(256), 0, stream,
                       rowptr, col, h1b, as1, ad1, b1, out1b, N);
    hipLaunchKernelGGL(gemm2_kernel, dim3((N + 63) / 64), dim3(256), 0, stream,
                       (const uint4*)out1b, W2T, a_s2, a_d2, (uint4*)h2b, as2, ad2, N);
    hipLaunchKernelGGL(agg2_kernel, dim3((N + 3) / 4), dim3(256), 0, stream,
                       rowptr, col, h2b, as2, ad2, b2, (float*)d_out, N);
}